// Round 13
// baseline (2435.055 us; speedup 1.0000x reference)
//
#include <hip/hip_runtime.h>
#include <hip/hip_bf16.h>

typedef __hip_bfloat16 bf16;
typedef __attribute__((ext_vector_type(8))) short short8;
typedef __attribute__((ext_vector_type(4))) float floatx4;

#define S_TOT 5440
#define BB 2
#define MTOT (BB * S_TOT)  // 10880

__device__ __forceinline__ float ldt(const void* p, long i, int t) {
  return t ? __bfloat162float(((const bf16*)p)[i]) : ((const float*)p)[i];
}
__device__ __forceinline__ void stt(void* p, long i, int t, float v) {
  if (t) ((bf16*)p)[i] = __float2bfloat16(v);
  else   ((float*)p)[i] = v;
}
__device__ __forceinline__ int rt(int code, int bf) { return code == 2 ? bf : code; }
__device__ __forceinline__ short f2bs(float f) {
  bf16 h = __float2bfloat16(f);
  return *(short*)&h;
}
__device__ __forceinline__ short ldbs(const void* p, long i, int t) {
  return t ? ((const short*)p)[i] : f2bs(((const float*)p)[i]);
}

__device__ __forceinline__ void lvl_of(int s, int& st, int& w, int& h) {
  if (s < 4096)      { st = 0;    w = 64; h = 64; }
  else if (s < 5120) { st = 4096; w = 32; h = 32; }
  else if (s < 5376) { st = 5120; w = 16; h = 16; }
  else               { st = 5376; w = 8;  h = 8;  }
}

// positional encoding for flattened index s, channel c (matches reference sine_pos)
__device__ __forceinline__ float pos_enc(int s, int c) {
  int st, w, h; lvl_of(s, st, w, h);
  int p = s - st, xi = p % w, yi = p / w;
  float v; int f;
  if (c < 128) { v = (yi + 1.0f) / (h + 1e-6f) * 6.28318f; f = c; }
  else         { v = (xi + 1.0f) / (w + 1e-6f) * 6.28318f; f = c - 128; }
  // 10000^((f>>1)*2/128) == 2^((f>>1)*0.20762050)
  float t = exp2f((float)(f >> 1) * 0.20762050f);
  float arg = v / t;
  return (f & 1) ? cosf(arg) : sinf(arg);
}

// ---------------- dtype detection: ln1_s == ones ----------------
__global__ void detect_kernel(const void* __restrict__ ones_vec, int* __restrict__ flag) {
  unsigned u = *(const unsigned*)ones_vec;
  *flag = (u == 0x3F800000u) ? 0 : 1;
}

// ---------------- zero fill ----------------
__global__ __launch_bounds__(256) void zero_kernel(float* __restrict__ p, int n) {
  int i = blockIdx.x * 256 + threadIdx.x;
  if (i < n) p[i] = 0.f;
}

// ---------------- weight transpose: out[n*K+k] = in[k*N+n] (bf16 out) ----------------
__global__ __launch_bounds__(256) void wtrans_kernel(const int* __restrict__ dflag,
    const void* __restrict__ in, short* __restrict__ out, int K, int N) {
  int bf = *dflag;
  long total = (long)N * K;
  long idx = (long)blockIdx.x * 256 + threadIdx.x;
  if (idx >= total) return;
  long n = idx / K, k = idx - n * K;
  out[idx] = ldbs(in, k * (long)N + n, bf);
}

// ---------------- conv weight transpose: out[lvl][oc][tap*256+c] = in[lvl][oc][c][tap] ----------------
__global__ __launch_bounds__(256) void wconvt_kernel(const int* __restrict__ dflag,
    const void* __restrict__ in, short* __restrict__ out) {
  int bf = *dflag;
  int idx = blockIdx.x * 256 + threadIdx.x;
  if (idx >= 4 * 256 * 2304) return;
  int k = idx % 2304;     // tap*256 + c
  int r = idx / 2304;     // lvl*256 + oc
  int tap = k >> 8, c = k & 255;
  out[idx] = ldbs(in, ((long)r * 256 + c) * 9 + tap, bf);
}

// ---------------- MFMA bf16 GEMM, fp32 accumulate ----------------
// C[M,N] = A[M,K] @ B. Block 64m x 128n, BK=32, 4 waves of 32x64.
// tBT=1: B is pre-transposed bf16 [N][K] (ldb=K). tBT=0: B is runtime-typed [K][N].
// flags: 1=bias per N (bias2+Nsplit for tail cols), 2=bias per M, 4=relu, 8=accum.
// ksplit>1: grid.z = batch*ksplit; each block covers K/ksplit; epilogue fp32 atomicAdd
//           into pre-zeroed C (bias applied by slice 0; no relu/accum support).
__global__ __launch_bounds__(256) void mgemm_kernel(
    const int* __restrict__ dflag,
    const void* __restrict__ A, const void* __restrict__ Bm,
    const void* __restrict__ bias, const void* __restrict__ bias2, void* __restrict__ C,
    int M, int N, int K, int lda, int ldb, int ldc, int Nsplit,
    long sA, long sB, long sC, long oB, long oBias, long oC,
    int flags, int tAc, int tBc, int tCc, int tBT, int ksplit) {
  int bf = *dflag;
  int tA = rt(tAc, bf), tB = rt(tBc, bf), tC = rt(tCc, bf);
  int bz = blockIdx.z, ks = 0;
  if (ksplit > 1) { bz = blockIdx.z / ksplit; ks = blockIdx.z - bz * ksplit; }
  int Kc = K / ksplit;
  int kbeg = ks * Kc, kend = kbeg + Kc;
  long baseA = (long)bz * sA;
  long baseC = (long)bz * sC + oC;
  int m0 = blockIdx.y * 64, n0 = blockIdx.x * 128;
  int tid = threadIdx.x;
  int wave = tid >> 6, lane = tid & 63;
  int wm = wave >> 1, wn = wave & 1;
  int quad = lane >> 4, l16 = lane & 15;

  __shared__ __align__(16) short As[64][40];
  __shared__ __align__(16) short Bs[128][40];

  floatx4 acc[2][4];
  #pragma unroll
  for (int i = 0; i < 2; ++i)
    #pragma unroll
    for (int j = 0; j < 4; ++j) acc[i][j] = floatx4{0.f, 0.f, 0.f, 0.f};

  int am_ = tid >> 2;
  int ak  = (tid & 3) * 8;
  // old-path B map
  int bk2 = tid >> 4;
  int bnc = tid & 15;
  int bcol = n0 + bnc * 8;
  if (bcol + 8 > N) bcol = N - 8;
  long cbO = (long)bz * sB + oB + bcol;
  // tBT-path B map
  int bn_ = tid & 127;
  int bkc = (tid >> 7) * 16;
  int brow = n0 + bn_; if (brow >= N) brow = N - 1;

  auto loadA = [&](int kx, short8& v) {
    long src = baseA + (long)(m0 + am_) * lda + kx + ak;
    if (tA) v = *(const short8*)((const short*)A + src);
    else {
      const float* f = (const float*)A + src;
      floatx4 f0 = *(const floatx4*)f, f1 = *(const floatx4*)(f + 4);
      v[0]=f2bs(f0[0]); v[1]=f2bs(f0[1]); v[2]=f2bs(f0[2]); v[3]=f2bs(f0[3]);
      v[4]=f2bs(f1[0]); v[5]=f2bs(f1[1]); v[6]=f2bs(f1[2]); v[7]=f2bs(f1[3]);
    }
  };
  auto loadBold = [&](int krow, short8& v) {
    if (tB) v = *(const short8*)((const short*)Bm + (long)krow * ldb + cbO);
    else {
      const float* f = (const float*)Bm + (long)krow * ldb + cbO;
      floatx4 f0 = *(const floatx4*)f, f1 = *(const floatx4*)(f + 4);
      v[0]=f2bs(f0[0]); v[1]=f2bs(f0[1]); v[2]=f2bs(f0[2]); v[3]=f2bs(f0[3]);
      v[4]=f2bs(f1[0]); v[5]=f2bs(f1[1]); v[6]=f2bs(f1[2]); v[7]=f2bs(f1[3]);
    }
  };
  auto loadBT = [&](int kx, short8& v0, short8& v1) {
    const short* p = (const short*)Bm + (long)brow * ldb + kx + bkc;
    v0 = *(const short8*)p;
    v1 = *(const short8*)(p + 8);
  };

  short8 vA, vB0, vB1;
  loadA(kbeg, vA);
  if (tBT) loadBT(kbeg, vB0, vB1);
  else { loadBold(kbeg + bk2, vB0); loadBold(kbeg + bk2 + 16, vB1); }

  for (int k0 = kbeg; k0 < kend; k0 += 32) {
    if (k0 != kbeg) __syncthreads();
    *(short8*)&As[am_][ak] = vA;
    if (tBT) {
      *(short8*)&Bs[bn_][bkc]     = vB0;
      *(short8*)&Bs[bn_][bkc + 8] = vB1;
    } else {
      #pragma unroll
      for (int j = 0; j < 8; ++j) {
        Bs[bnc * 8 + j][bk2]      = vB0[j];
        Bs[bnc * 8 + j][bk2 + 16] = vB1[j];
      }
    }
    __syncthreads();
    int kn = k0 + 32;
    if (kn < kend) {
      loadA(kn, vA);
      if (tBT) loadBT(kn, vB0, vB1);
      else { loadBold(kn + bk2, vB0); loadBold(kn + bk2 + 16, vB1); }
    }
    short8 af[2], bfr[4];
    #pragma unroll
    for (int i = 0; i < 2; ++i)
      af[i] = *(const short8*)&As[wm * 32 + i * 16 + l16][quad * 8];
    #pragma unroll
    for (int j = 0; j < 4; ++j)
      bfr[j] = *(const short8*)&Bs[wn * 64 + j * 16 + l16][quad * 8];
    #pragma unroll
    for (int i = 0; i < 2; ++i)
      #pragma unroll
      for (int j = 0; j < 4; ++j)
        acc[i][j] = __builtin_amdgcn_mfma_f32_16x16x32_bf16(af[i], bfr[j], acc[i][j], 0, 0, 0);
  }

  #pragma unroll
  for (int i = 0; i < 2; ++i) {
    int m = m0 + wm * 32 + i * 16 + quad * 4;
    #pragma unroll
    for (int j = 0; j < 4; ++j) {
      int n = n0 + wn * 64 + j * 16 + l16;
      if (n >= N) continue;
      float bn_add = 0.f;
      if ((flags & 1) && ks == 0) {
        bn_add = (bias2 != nullptr && n >= Nsplit) ? ldt(bias2, n - Nsplit, tB)
                                                   : ldt(bias, oBias + n, tB);
      }
      #pragma unroll
      for (int r = 0; r < 4; ++r) {
        float v = acc[i][j][r] + bn_add;
        if ((flags & 2) && ks == 0) v += ldt(bias, oBias + m + r, tB);
        long off = baseC + (long)(m + r) * ldc + n;
        if (ksplit > 1) {
          atomicAdd((float*)C + off, v);
        } else {
          if (flags & 8) v += ldt(C, off, tC);
          if (flags & 4) v = fmaxf(v, 0.f);
          stt(C, off, tC, v);
        }
      }
    }
  }
}

// ---------------- encoder GEMM v2: K=256 resident A-tile, B fragments direct from L2 ----------------
// do_sm=1: softmax over each 16-col group for n >= Nsplit (fused attention-weight softmax).
__global__ __launch_bounds__(256) void egemm_kernel(const int* __restrict__ dflag,
    const void* __restrict__ A, const short* __restrict__ Bt,
    const void* __restrict__ bias, const void* __restrict__ bias2, void* __restrict__ C,
    int N, int ldc, int Nsplit, int tAc, int tCc, int do_sm) {
  int bf = *dflag;
  int tA = rt(tAc, bf), tC = rt(tCc, bf);
  int m0 = blockIdx.y * 64, n0 = blockIdx.x * 128;
  int tid = threadIdx.x;
  int wave = tid >> 6, lane = tid & 63;
  int wm = wave >> 1, wn = wave & 1;
  int quad = lane >> 4, l16 = lane & 15;

  __shared__ __align__(16) short As[64][264];

  floatx4 acc[2][4];
  #pragma unroll
  for (int i = 0; i < 2; ++i)
    #pragma unroll
    for (int j = 0; j < 4; ++j) acc[i][j] = floatx4{0.f, 0.f, 0.f, 0.f};

  // stage full A tile (64 x 256) once
  {
    int r = tid >> 2, c0 = (tid & 3) * 64;
    if (tA) {
      const short* s = (const short*)A + (long)(m0 + r) * 256 + c0;
      #pragma unroll
      for (int c = 0; c < 64; c += 8)
        *(short8*)&As[r][c0 + c] = *(const short8*)(s + c);
    } else {
      const float* f = (const float*)A + (long)(m0 + r) * 256 + c0;
      #pragma unroll
      for (int c = 0; c < 64; c += 8) {
        floatx4 f0 = *(const floatx4*)(f + c);
        floatx4 f1 = *(const floatx4*)(f + c + 4);
        short8 v;
        v[0]=f2bs(f0[0]); v[1]=f2bs(f0[1]); v[2]=f2bs(f0[2]); v[3]=f2bs(f0[3]);
        v[4]=f2bs(f1[0]); v[5]=f2bs(f1[1]); v[6]=f2bs(f1[2]); v[7]=f2bs(f1[3]);
        *(short8*)&As[r][c0 + c] = v;
      }
    }
  }
  __syncthreads();

  // barrier-free K loop; B fragments straight from L2
  #pragma unroll
  for (int k0 = 0; k0 < 256; k0 += 32) {
    short8 af[2], bfr[4];
    #pragma unroll
    for (int j = 0; j < 4; ++j)
      bfr[j] = *(const short8*)(Bt + (long)(n0 + wn * 64 + j * 16 + l16) * 256 + k0 + quad * 8);
    #pragma unroll
    for (int i = 0; i < 2; ++i)
      af[i] = *(const short8*)&As[wm * 32 + i * 16 + l16][k0 + quad * 8];
    #pragma unroll
    for (int i = 0; i < 2; ++i)
      #pragma unroll
      for (int j = 0; j < 4; ++j)
        acc[i][j] = __builtin_amdgcn_mfma_f32_16x16x32_bf16(af[i], bfr[j], acc[i][j], 0, 0, 0);
  }

  #pragma unroll
  for (int i = 0; i < 2; ++i) {
    int m = m0 + wm * 32 + i * 16 + quad * 4;
    #pragma unroll
    for (int j = 0; j < 4; ++j) {
      int n = n0 + wn * 64 + j * 16 + l16;
      if (n >= N) continue;
      float bn_add = (bias2 != nullptr && n >= Nsplit) ? ldt(bias2, n - Nsplit, bf)
                                                       : ldt(bias, n, bf);
      float vv[4];
      #pragma unroll
      for (int r = 0; r < 4; ++r) vv[r] = acc[i][j][r] + bn_add;
      if (do_sm && n0 + wn * 64 + j * 16 >= Nsplit) {
        // softmax over the 16 lanes of this quad group (one aw group per row)
        #pragma unroll
        for (int r = 0; r < 4; ++r) {
          float x = vv[r];
          float mx = x;
          #pragma unroll
          for (int msk = 1; msk < 16; msk <<= 1)
            mx = fmaxf(mx, __shfl_xor(mx, msk));
          float e = expf(x - mx);
          float ssum = e;
          #pragma unroll
          for (int msk = 1; msk < 16; msk <<= 1)
            ssum += __shfl_xor(ssum, msk);
          vv[r] = e / ssum;
        }
      }
      #pragma unroll
      for (int r = 0; r < 4; ++r)
        stt(C, (long)(m + r) * ldc + n, tC, vv[r]);
    }
  }
}

// ---------------- fused FFN v3 (measured-best): weights direct from L2, 2 barriers/chunk ----------------
// out = relu(src@W1 + b1) @ W2 + b2. W1t [2048][256], W2t [256][2048].
__global__ __launch_bounds__(256) void ffn_kernel(const int* __restrict__ dflag,
    const float* __restrict__ src, const short* __restrict__ W1t, const void* __restrict__ b1,
    const short* __restrict__ W2t, const void* __restrict__ b2, bf16* __restrict__ out) {
  int bf = *dflag;
  long m0 = (long)blockIdx.x * 32;
  int tid = threadIdx.x;
  int wn = tid >> 6, lane = tid & 63;
  int quad = lane >> 4, l16 = lane & 15;

  __shared__ __align__(16) short As[32][264];  // src tile, K=256 resident
  __shared__ __align__(16) short Hs[32][136];  // hidden chunk (128 k)

  floatx4 acc2[2][4];
  #pragma unroll
  for (int i = 0; i < 2; ++i)
    #pragma unroll
    for (int j = 0; j < 4; ++j) acc2[i][j] = floatx4{0.f, 0.f, 0.f, 0.f};

  // stage src tile once (32 x 256)
  {
    int r = tid >> 3, c0 = (tid & 7) * 32;
    const float* sp = src + (m0 + r) * 256 + c0;
    #pragma unroll
    for (int c = 0; c < 32; c += 8) {
      floatx4 f0 = *(const floatx4*)(sp + c);
      floatx4 f1 = *(const floatx4*)(sp + c + 4);
      short8 v;
      v[0]=f2bs(f0[0]); v[1]=f2bs(f0[1]); v[2]=f2bs(f0[2]); v[3]=f2bs(f0[3]);
      v[4]=f2bs(f1[0]); v[5]=f2bs(f1[1]); v[6]=f2bs(f1[2]); v[7]=f2bs(f1[3]);
      *(short8*)&As[r][c0 + c] = v;
    }
  }
  __syncthreads();

  for (int ch = 0; ch < 16; ++ch) {
    floatx4 acc1[2][2];
    #pragma unroll
    for (int i = 0; i < 2; ++i)
      #pragma unroll
      for (int j = 0; j < 2; ++j) acc1[i][j] = floatx4{0.f, 0.f, 0.f, 0.f};

    // stage1: H = relu(src @ W1chunk) — barrier-free K loop, W1 direct from L2
    #pragma unroll
    for (int k1 = 0; k1 < 256; k1 += 32) {
      short8 af[2], bfr[2];
      #pragma unroll
      for (int j = 0; j < 2; ++j)
        bfr[j] = *(const short8*)(W1t + (long)(ch * 128 + wn * 32 + j * 16 + l16) * 256 + k1 + quad * 8);
      #pragma unroll
      for (int i = 0; i < 2; ++i)
        af[i] = *(const short8*)&As[i * 16 + l16][k1 + quad * 8];
      #pragma unroll
      for (int i = 0; i < 2; ++i)
        #pragma unroll
        for (int j = 0; j < 2; ++j)
          acc1[i][j] = __builtin_amdgcn_mfma_f32_16x16x32_bf16(af[i], bfr[j], acc1[i][j], 0, 0, 0);
    }

    __syncthreads();   // prev stage2 Hs reads done
    #pragma unroll
    for (int i = 0; i < 2; ++i)
      #pragma unroll
      for (int j = 0; j < 2; ++j) {
        int nl = wn * 32 + j * 16 + l16;
        float bb = ldt(b1, (long)ch * 128 + nl, bf);
        #pragma unroll
        for (int r = 0; r < 4; ++r) {
          float hv = fmaxf(acc1[i][j][r] + bb, 0.f);
          Hs[i * 16 + quad * 4 + r][nl] = f2bs(hv);
        }
      }
    __syncthreads();   // Hs visible

    // stage2: acc2 += H @ W2chunk — barrier-free, W2 direct from L2
    #pragma unroll
    for (int t2 = 0; t2 < 8; ++t2) {
      int nh = t2 >> 2, k2 = (t2 & 3) * 32;
      short8 ah[2], bfr[2];
      #pragma unroll
      for (int j = 0; j < 2; ++j)
        bfr[j] = *(const short8*)(W2t + (long)(nh * 128 + wn * 32 + j * 16 + l16) * 2048 + ch * 128 + k2 + quad * 8);
      #pragma unroll
      for (int i = 0; i < 2; ++i)
        ah[i] = *(const short8*)&Hs[i * 16 + l16][k2 + quad * 8];
      #pragma unroll
      for (int i = 0; i < 2; ++i)
        #pragma unroll
        for (int j = 0; j < 2; ++j)
          acc2[i][nh * 2 + j] =
              __builtin_amdgcn_mfma_f32_16x16x32_bf16(ah[i], bfr[j], acc2[i][nh * 2 + j], 0, 0, 0);
    }
  }

  #pragma unroll
  for (int i = 0; i < 2; ++i) {
    long m = m0 + i * 16 + quad * 4;
    #pragma unroll
    for (int nh = 0; nh < 2; ++nh)
      #pragma unroll
      for (int j = 0; j < 2; ++j) {
        int n = nh * 128 + wn * 32 + j * 16 + l16;
        float bb = ldt(b2, n, bf);
        #pragma unroll
        for (int r = 0; r < 4; ++r)
          out[(m + r) * 256 + n] = __float2bfloat16(acc2[i][nh * 2 + j][r] + bb);
      }
  }
}

// ---------------- 3x3 conv as MFMA implicit GEMM (pre-transposed bf16 weights) ----------------
__global__ __launch_bounds__(256) void mconv_kernel(const short* __restrict__ Wc,
    const float* __restrict__ X, float* __restrict__ Y, int H, int Wd, int lw) {
  int bz = blockIdx.z;
  int HW = H * Wd;
  const float* Xb = X + (long)bz * 256 * HW;
  float* Yb = Y + (long)bz * 256 * HW;
  int m0 = blockIdx.y * 64, n0 = blockIdx.x * 128;
  int tid = threadIdx.x;
  int wave = tid >> 6, lane = tid & 63;
  int wm = wave >> 1, wn = wave & 1;
  int quad = lane >> 4, l16 = lane & 15;

  __shared__ __align__(16) short As[64][40];
  __shared__ __align__(16) short Bs[128][40];

  floatx4 acc[2][4];
  #pragma unroll
  for (int i = 0; i < 2; ++i)
    #pragma unroll
    for (int j = 0; j < 4; ++j) acc[i][j] = floatx4{0.f, 0.f, 0.f, 0.f};

  int am_ = tid >> 2;
  int ak  = (tid & 3) * 8;
  int bn_ = tid & 127;
  int bkc = (tid >> 7) * 16;
  int gn  = n0 + bn_; if (gn >= HW) gn = HW - 1;
  int y = gn >> lw, x = gn & (Wd - 1);

  const short* Arow = Wc + (long)(m0 + am_) * 2304 + ak;

  short8 vA;
  float rB[16];
  auto pre = [&](int k0) {
    vA = *(const short8*)(Arow + k0);
    int tap = k0 >> 8;
    int dy = tap / 3 - 1, dx = tap % 3 - 1;
    bool ok = ((unsigned)(y + dy) < (unsigned)H) && ((unsigned)(x + dx) < (unsigned)Wd);
    const float* xp = Xb + (long)((k0 & 255) + bkc) * HW + gn + dy * Wd + dx;
    #pragma unroll
    for (int j = 0; j < 16; ++j)
      rB[j] = ok ? xp[(long)j * HW] : 0.f;
  };

  pre(0);
  for (int k0 = 0; k0 < 2304; k0 += 32) {
    if (k0) __syncthreads();
    *(short8*)&As[am_][ak] = vA;
    #pragma unroll
    for (int j = 0; j < 16; ++j) Bs[bn_][bkc + j] = f2bs(rB[j]);
    __syncthreads();
    if (k0 + 32 < 2304) pre(k0 + 32);
    short8 af[2], bfr[4];
    #pragma unroll
    for (int i = 0; i < 2; ++i)
      af[i] = *(const short8*)&As[wm * 32 + i * 16 + l16][quad * 8];
    #pragma unroll
    for (int j = 0; j < 4; ++j)
      bfr[j] = *(const short8*)&Bs[wn * 64 + j * 16 + l16][quad * 8];
    #pragma unroll
    for (int i = 0; i < 2; ++i)
      #pragma unroll
      for (int j = 0; j < 4; ++j)
        acc[i][j] = __builtin_amdgcn_mfma_f32_16x16x32_bf16(af[i], bfr[j], acc[i][j], 0, 0, 0);
  }

  #pragma unroll
  for (int i = 0; i < 2; ++i) {
    int m = m0 + wm * 32 + i * 16 + quad * 4;
    #pragma unroll
    for (int j = 0; j < 4; ++j) {
      int n = n0 + wn * 64 + j * 16 + l16;
      if (n >= HW) continue;
      #pragma unroll
      for (int r = 0; r < 4; ++r)
        Yb[(long)(m + r) * HW + n] = acc[i][j][r];
    }
  }
}

// ---------------- GroupNorm in-place (fp32 X) ----------------
__global__ __launch_bounds__(256) void gn_kernel(const int* __restrict__ dflag,
    float* __restrict__ X, const void* __restrict__ gs, const void* __restrict__ gb,
    long po, int HW, int relu) {
  int bf = *dflag;
  int g = blockIdx.x, b = blockIdx.y;
  float* base = X + ((long)b * 256 + g * 8) * HW;
  int n = 8 * HW;
  int t = threadIdx.x;
  float s1 = 0.f, s2 = 0.f;
  for (int i = t; i < n; i += 256) { float v = base[i]; s1 += v; s2 += v * v; }
  __shared__ float r1[256], r2[256];
  r1[t] = s1; r2[t] = s2; __syncthreads();
  for (int sh = 128; sh > 0; sh >>= 1) {
    if (t < sh) { r1[t] += r1[t + sh]; r2[t] += r2[t + sh]; }
    __syncthreads();
  }
  float mu = r1[0] / n;
  float var = fmaxf(r2[0] / n - mu * mu, 0.f);
  float inv = rsqrtf(var + 1e-5f);
  for (int i = t; i < n; i += 256) {
    int c = g * 8 + i / HW;
    float v = (base[i] - mu) * inv * ldt(gs, po + c, bf) + ldt(gb, po + c, bf);
    if (relu) v = fmaxf(v, 0.f);
    base[i] = v;
  }
}

// ---------------- bilinear 0.5x downsample (2x2 avg) added into target ----------------
__global__ __launch_bounds__(256) void dsadd_kernel(float* __restrict__ T,
    const float* __restrict__ P, int H, int Wd) {
  int idx = blockIdx.x * 256 + threadIdx.x;
  int total = BB * 256 * H * Wd;
  if (idx >= total) return;
  int x = idx % Wd, y = (idx / Wd) % H;
  int bc = idx / (Wd * H);
  const float* Pp = P + (((long)bc * (2 * H) + 2 * y) * (2 * Wd) + 2 * x);
  T[idx] += 0.25f * (Pp[0] + Pp[1] + Pp[2 * Wd] + Pp[2 * Wd + 1]);
}

// ---------------- build src (fp32) from FPN maps ----------------
__global__ __launch_bounds__(256) void srcbuild_kernel(const float* __restrict__ O0,
    const float* __restrict__ O1, const float* __restrict__ O2, const float* __restrict__ O3,
    float* __restrict__ src) {
  int idx = blockIdx.x * 256 + threadIdx.x;
  if (idx >= MTOT * 256) return;
  int c = idx & 255;
  int bs = idx >> 8;
  int s = bs % S_TOT, b = bs / S_TOT;
  int st, w, h; lvl_of(s, st, w, h);
  const float* O = (s < 4096) ? O0 : (s < 5120) ? O1 : (s < 5376) ? O2 : O3;
  int HW = w * h;
  src[idx] = O[((long)(b * 256 + c)) * HW + (s - st)];
}

// ---------------- layer-0 q = bf16(src + pos) ----------------
__global__ __launch_bounds__(256) void qinit_kernel(const float* __restrict__ src,
    bf16* __restrict__ q) {
  int idx = blockIdx.x * 256 + threadIdx.x;
  if (idx >= MTOT * 256) return;
  int c = idx & 255;
  int bs = idx >> 8;
  int s = bs % S_TOT;
  q[idx] = __float2bfloat16(src[idx] + pos_enc(s, c));
}

// ---------------- multi-scale deformable sampling (fused off|aw layout) ----------------
__global__ __launch_bounds__(256) void deform_kernel(const bf16* __restrict__ value,
    const bf16* __restrict__ oaw, bf16* __restrict__ attn) {
  int idx = blockIdx.x * 256 + threadIdx.x;
  if (idx >= MTOT * 256) return;
  int d = idx & 31;
  int h = (idx >> 5) & 7;
  int bs = idx >> 8;
  int s = bs % S_TOT, b = bs / S_TOT;
  int stS, wS, hS; lvl_of(s, stS, wS, hS);
  int pl = s - stS;
  float rx = ((pl % wS) + 0.5f) / wS;
  float ry = ((pl / wS) + 0.5f) / hS;
  const bf16* offr = oaw + (long)bs * 384 + h * 32;
  const bf16* awr  = oaw + (long)bs * 384 + 256 + h * 16;
  const bf16* vbase = value + (long)b * S_TOT * 256 + h * 32 + d;
  const int LW[4] = {64, 32, 16, 8}, LST[4] = {0, 4096, 5120, 5376};
  float acc = 0.f;
  #pragma unroll
  for (int l = 0; l < 4; ++l) {
    int w = LW[l], hh = LW[l], st = LST[l];
    #pragma unroll
    for (int p = 0; p < 4; ++p) {
      float ox = __bfloat162float(offr[l * 8 + p * 2 + 0]);
      float oy = __bfloat162float(offr[l * 8 + p * 2 + 1]);
      float x = rx * w + ox - 0.5f;
      float y = ry * hh + oy - 0.5f;
      float x0f = floorf(x), y0f = floorf(y);
      int x0 = (int)x0f, y0 = (int)y0f;
      float fx = x - x0f, fy = y - y0f;
      float a = __bfloat162float(awr[l * 4 + p]);
      float sample = 0.f;
      #pragma unroll
      for (int ty2 = 0; ty2 < 2; ++ty2) {
        int yi = y0 + ty2;
        float wy = ty2 ? fy : 1.f - fy;
        bool vy = (yi >= 0) && (yi < hh);
        int yc = min(max(yi, 0), hh - 1);
        #pragma unroll
        for (int tx2 = 0; tx2 < 2; ++tx2) {
          int xi = x0 + tx2;
          float wx = tx2 ? fx : 1.f - fx;
          bool vx = (xi >= 0) && (xi < w);
          int xc = min(max(xi, 0), w - 1);
          float v = __bfloat162float(vbase[(long)(st + yc * w + xc) * 256]);
          if (vx && vy) sample += wy * wx * v;
        }
      }
      acc += a * sample;
    }
  }
  attn[idx] = __float2bfloat16(acc);
}

// ---------------- LayerNorm(src + resid_bf16), wave-per-row, optional q = bf16(out + pos) ----------------
__global__ __launch_bounds__(256) void ln_kernel(const int* __restrict__ dflag,
    float* __restrict__ src, const bf16* __restrict__ resid,
    const void* __restrict__ g, const void* __restrict__ b, bf16* __restrict__ qout) {
  int bf = *dflag;
  long r = (long)blockIdx.x * 4 + (threadIdx.x >> 6);
  int lane = threadIdx.x & 63;
  float* x = src + r * 256;
  const bf16* a = resid + r * 256;
  float v[4];
  float s1 = 0.f, s2 = 0.f;
  #pragma unroll
  for (int k = 0; k < 4; ++k) {
    int c = lane + 64 * k;
    float t = x[c] + __bfloat162float(a[c]);
    v[k] = t; s1 += t; s2 += t * t;
  }
  #pragma unroll
  for (int msk = 1; msk < 64; msk <<= 1) {
    s1 += __shfl_xor(s1, msk);
    s2 += __shfl_xor(s2, msk);
  }
  float mu = s1 * (1.f / 256.f);
  float var = fmaxf(s2 * (1.f / 256.f) - mu * mu, 0.f);
  float inv = rsqrtf(var + 1e-5f);
  int s = (int)(r % S_TOT);
  #pragma unroll
  for (int k = 0; k < 4; ++k) {
    int c = lane + 64 * k;
    float o = (v[k] - mu) * inv * ldt(g, c, bf) + ldt(b, c, bf);
    x[c] = o;
    if (qout) qout[r * 256 + c] = __float2bfloat16(o + pos_enc(s, c));
  }
}

// ---------------- unflatten src -> out chunks 1..4 ----------------
__global__ __launch_bounds__(256) void unflat_kernel(const int* __restrict__ dflag,
    const float* __restrict__ src, void* __restrict__ out) {
  int bf = *dflag;
  int idx = blockIdx.x * 256 + threadIdx.x;
  if (idx >= MTOT * 256) return;
  int c = idx & 255;
  int bs = idx >> 8;
  int s = bs % S_TOT, b = bs / S_TOT;
  int st, w, h; lvl_of(s, st, w, h);
  int HW = w * h;
  long base = (s < 4096) ? 2097152L : (s < 5120) ? 4194304L : (s < 5376) ? 4718592L : 4849664L;
  stt(out, base + ((long)(b * 256 + c)) * HW + (s - st), bf, src[idx]);
}

// ---------------- sentinel ----------------
__global__ __launch_bounds__(256) void sentinel_kernel(float* __restrict__ out, int n) {
  int i = blockIdx.x * 256 + threadIdx.x;
  if (i < n) out[i] = 999.0f;
}

// =====================================================================
extern "C" void kernel_launch(void* const* d_in, const int* in_sizes, int n_in,
                              void* d_out, int out_size, void* d_ws, size_t ws_size,
                              hipStream_t stream) {
  (void)in_sizes; (void)n_in;
  // 7,659,520 activations + 64 flag + 638,976 transposed-weight floats
  const size_t NEED = (7659520ull + 64ull + 638976ull) * 4ull;
  if (ws_size < NEED) {
    int nf = out_size / 2;
    sentinel_kernel<<<(nf + 255) / 256, 256, 0, stream>>>((float*)d_out, nf);
    return;
  }

  const void* feat[4] = {d_in[0], d_in[1], d_in[2], d_in[3]};
  const void* latw[4] = {d_in[4], d_in[5], d_in[6], d_in[7]};
  const void *latgns = d_in[8], *latgnb = d_in[9];
  const void* outw = d_in[10];
  const void *outgns = d_in[11], *outgnb = d_in[12];
  const void *offw = d_in[13], *offb_ = d_in[14], *aww = d_in[15], *awb_ = d_in[16];
  const void *valw = d_in[17], *valb_ = d_in[18], *projw = d_in[19], *projb_ = d_in[20];
  const void *f1w = d_in[21], *f1b = d_in[22], *f2w = d_in[23], *f2b = d_in[24];
  const void *ln1s = d_in[25], *ln1b = d_in[26], *ln2s = d_in[27], *ln2b = d_in[28];
  const void *maskw = d_in[29], *maskb = d_in[30];

  float* W = (float*)d_ws;
  float* srcb  = W;
  float* fpn_a = W;
  bf16*  oawbf = (bf16*)(W + 2785280);
  bf16*  tmpbf = oawbf;
  bf16*  qbf   = (bf16*)(W + 4874240);
  bf16*  valbf = (bf16*)(W + 6266880);
  float* ObF   = W + 4874240;
  float* Ob[4] = {ObF, ObF + 2097152, ObF + 2621440, ObF + 2752512};
  int*   dflag = (int*)(W + 7659520);
  short* wtS   = (short*)(W + 7659584);
  short* valt  = wtS;             // [256][256]
  short* projt = wtS + 65536;     // [256][256]
  short* oawt  = wtS + 131072;    // [384][256]
  short* w1t   = wtS + 229376;    // [2048][256]
  short* w2t   = wtS + 753664;    // [256][2048]
  // conv weights (bf16, [4][256][2304]) live in the encoder-phase oawbf region;
  // FPN finishes before the encoder overwrites it.
  short* wconvt = (short*)(W + 2785280);   // 2,359,296 shorts, ends at W+3964928

  detect_kernel<<<1, 1, 0, stream>>>(ln1s, dflag);
  // pre-transpose encoder weights to bf16 [N][K]
  wtrans_kernel<<<(65536 + 255) / 256, 256, 0, stream>>>(dflag, valw, valt, 256, 256);
  wtrans_kernel<<<(65536 + 255) / 256, 256, 0, stream>>>(dflag, projw, projt, 256, 256);
  wtrans_kernel<<<(65536 + 255) / 256, 256, 0, stream>>>(dflag, offw, oawt, 256, 256);
  wtrans_kernel<<<(32768 + 255) / 256, 256, 0, stream>>>(dflag, aww, oawt + 65536, 256, 128);
  wtrans_kernel<<<(524288 + 255) / 256, 256, 0, stream>>>(dflag, f1w, w1t, 256, 2048);
  wtrans_kernel<<<(524288 + 255) / 256, 256, 0, stream>>>(dflag, f2w, w2t, 2048, 256);
  wconvt_kernel<<<(2359296 + 255) / 256, 256, 0, stream>>>(dflag, outw, wconvt);

  const int M = MTOT;
  auto mgemm = [&](const void* A, const void* B, const void* bias, const void* bias2,
                   void* C, int Mi, int Ni, int Ki, int lda, int ldb, int ldc, int Nsplit,
                   long sA, long sB, long sC, long oB, long oBias, long oC,
                   int batch, int flags, int tA, int tB, int tC, int tBT, int ksplit) {
    dim3 g((Ni + 127) / 128, Mi / 64, batch * ksplit);
    mgemm_kernel<<<g, 256, 0, stream>>>(dflag, A, B, bias, bias2, C, Mi, Ni, Ki,
                                        lda, ldb, ldc, Nsplit,
                                        sA, sB, sC, oB, oBias, oC, flags, tA, tB, tC, tBT,
                                        ksplit);
  };
  auto egemm = [&](const void* A, const short* Bt, const void* bias, const void* bias2,
                   void* C, int Ni, int ldc, int Nsplit, int tA, int tC, int do_sm) {
    dim3 g((Ni + 127) / 128, M / 64, 1);
    egemm_kernel<<<g, 256, 0, stream>>>(dflag, A, Bt, bias, bias2, C, Ni, ldc, Nsplit,
                                        tA, tC, do_sm);
  };

  // ---------------- FPN ----------------
  const int LVL[4] = {64, 32, 16, 8};
  const int LGW[4] = {6, 5, 4, 3};
  const int CIN[4] = {256, 512, 1024, 2048};
  const int KSP[4] = {1, 4, 8, 16};   // split-K for under-parallelized laterals
  for (int i = 0; i < 4; ++i) {
    int H = LVL[i], HW = H * H, Cin = CIN[i];
    int ksp = KSP[i];
    if (ksp > 1)
      zero_kernel<<<(BB * 256 * HW + 255) / 256, 256, 0, stream>>>(fpn_a, BB * 256 * HW);
    mgemm(latw[i], feat[i], nullptr, nullptr, fpn_a, 256, HW, Cin,
          Cin, HW, HW, 0, 0, (long)Cin * HW, (long)256 * HW, 0, 0, 0, BB, 0, 2, 2, 0, 0, ksp);
    gn_kernel<<<dim3(32, BB), 256, 0, stream>>>(dflag, fpn_a, latgns, latgnb,
                                                (long)i * 256, HW, 0);
    if (i > 0) {
      int total = BB * 256 * HW;
      dsadd_kernel<<<(total + 255) / 256, 256, 0, stream>>>(fpn_a, Ob[i - 1], H, H);
    }
    {
      dim3 g((HW + 127) / 128, 4, BB);
      mconv_kernel<<<g, 256, 0, stream>>>(wconvt + (long)i * 589824, fpn_a, Ob[i],
                                          H, H, LGW[i]);
    }
    gn_kernel<<<dim3(32, BB), 256, 0, stream>>>(dflag, Ob[i], outgns, outgnb,
                                                (long)i * 256, HW, 1);
  }

  srcbuild_kernel<<<(M * 256) / 256, 256, 0, stream>>>(Ob[0], Ob[1], Ob[2], Ob[3], srcb);
  // layer-0 q (runs after srcbuild fully consumed Ob; qbf aliases Ob[0] safely now)
  qinit_kernel<<<(M * 256) / 256, 256, 0, stream>>>(srcb, qbf);

  // ---------------- encoder layers (shared weights) ----------------
  for (int L = 0; L < 6; ++L) {
    egemm(srcb, valt, valb_, nullptr, valbf, 256, 256, 256, 0, 1, 0);
    egemm(qbf, oawt, offb_, awb_, oawbf, 384, 384, 256, 1, 1, 1);   // fused aw softmax
    deform_kernel<<<(M * 256) / 256, 256, 0, stream>>>(valbf, oawbf, qbf);
    egemm(qbf, projt, projb_, nullptr, tmpbf, 256, 256, 256, 1, 1, 0);
    ln_kernel<<<M / 4, 256, 0, stream>>>(dflag, srcb, tmpbf, ln1s, ln1b, nullptr);
    ffn_kernel<<<M / 32, 256, 0, stream>>>(dflag, srcb, w1t, f1b, w2t, f2b, tmpbf);
    ln_kernel<<<M / 4, 256, 0, stream>>>(dflag, srcb, tmpbf, ln2s, ln2b,
                                         (L < 5) ? qbf : nullptr);
  }

  // ---------------- outputs ----------------
  unflat_kernel<<<(M * 256) / 256, 256, 0, stream>>>(dflag, srcb, d_out);
  mgemm(maskw, d_out, maskb, nullptr, d_out, 256, 4096, 256,
        256, 4096, 4096, 0, 0, 1048576L, 1048576L, 2097152L, 0, 0, BB, 2, 2, 2, 2, 0, 1);
}

// Round 14
// 2276.679 us; speedup vs baseline: 1.0696x; 1.0696x over previous
//
#include <hip/hip_runtime.h>
#include <hip/hip_bf16.h>

typedef __hip_bfloat16 bf16;
typedef __attribute__((ext_vector_type(8))) short short8;
typedef __attribute__((ext_vector_type(4))) float floatx4;

#define S_TOT 5440
#define BB 2
#define MTOT (BB * S_TOT)  // 10880

__device__ __forceinline__ float ldt(const void* p, long i, int t) {
  return t ? __bfloat162float(((const bf16*)p)[i]) : ((const float*)p)[i];
}
__device__ __forceinline__ void stt(void* p, long i, int t, float v) {
  if (t) ((bf16*)p)[i] = __float2bfloat16(v);
  else   ((float*)p)[i] = v;
}
__device__ __forceinline__ int rt(int code, int bf) { return code == 2 ? bf : code; }
__device__ __forceinline__ short f2bs(float f) {
  bf16 h = __float2bfloat16(f);
  return *(short*)&h;
}
__device__ __forceinline__ short ldbs(const void* p, long i, int t) {
  return t ? ((const short*)p)[i] : f2bs(((const float*)p)[i]);
}

// async global->LDS 16B per lane (dest = ldsbase + lane*16)
__device__ __forceinline__ void gload_lds16(const short* g, short* l) {
  __builtin_amdgcn_global_load_lds(
      (const __attribute__((address_space(1))) void*)g,
      (__attribute__((address_space(3))) void*)l, 16, 0, 0);
}

__device__ __forceinline__ void lvl_of(int s, int& st, int& w, int& h) {
  if (s < 4096)      { st = 0;    w = 64; h = 64; }
  else if (s < 5120) { st = 4096; w = 32; h = 32; }
  else if (s < 5376) { st = 5120; w = 16; h = 16; }
  else               { st = 5376; w = 8;  h = 8;  }
}

// positional encoding for flattened index s, channel c (matches reference sine_pos)
__device__ __forceinline__ float pos_enc(int s, int c) {
  int st, w, h; lvl_of(s, st, w, h);
  int p = s - st, xi = p % w, yi = p / w;
  float v; int f;
  if (c < 128) { v = (yi + 1.0f) / (h + 1e-6f) * 6.28318f; f = c; }
  else         { v = (xi + 1.0f) / (w + 1e-6f) * 6.28318f; f = c - 128; }
  float t = exp2f((float)(f >> 1) * 0.20762050f);
  float arg = v / t;
  return (f & 1) ? cosf(arg) : sinf(arg);
}

// ---------------- dtype detection: ln1_s == ones ----------------
__global__ void detect_kernel(const void* __restrict__ ones_vec, int* __restrict__ flag) {
  unsigned u = *(const unsigned*)ones_vec;
  *flag = (u == 0x3F800000u) ? 0 : 1;
}

// ---------------- zero fill ----------------
__global__ __launch_bounds__(256) void zero_kernel(float* __restrict__ p, int n) {
  int i = blockIdx.x * 256 + threadIdx.x;
  if (i < n) p[i] = 0.f;
}

// ---------------- weight transpose: out[n*K+k] = in[k*N+n] (bf16 out) ----------------
__global__ __launch_bounds__(256) void wtrans_kernel(const int* __restrict__ dflag,
    const void* __restrict__ in, short* __restrict__ out, int K, int N) {
  int bf = *dflag;
  long total = (long)N * K;
  long idx = (long)blockIdx.x * 256 + threadIdx.x;
  if (idx >= total) return;
  long n = idx / K, k = idx - n * K;
  out[idx] = ldbs(in, k * (long)N + n, bf);
}

// ---------------- conv weight transpose: out[lvl][oc][tap*256+c] = in[lvl][oc][c][tap] ----------------
__global__ __launch_bounds__(256) void wconvt_kernel(const int* __restrict__ dflag,
    const void* __restrict__ in, short* __restrict__ out) {
  int bf = *dflag;
  int idx = blockIdx.x * 256 + threadIdx.x;
  if (idx >= 4 * 256 * 2304) return;
  int k = idx % 2304;     // tap*256 + c
  int r = idx / 2304;     // lvl*256 + oc
  int tap = k >> 8, c = k & 255;
  out[idx] = ldbs(in, ((long)r * 256 + c) * 9 + tap, bf);
}

// ---------------- MFMA bf16 GEMM, fp32 accumulate ----------------
__global__ __launch_bounds__(256) void mgemm_kernel(
    const int* __restrict__ dflag,
    const void* __restrict__ A, const void* __restrict__ Bm,
    const void* __restrict__ bias, const void* __restrict__ bias2, void* __restrict__ C,
    int M, int N, int K, int lda, int ldb, int ldc, int Nsplit,
    long sA, long sB, long sC, long oB, long oBias, long oC,
    int flags, int tAc, int tBc, int tCc, int tBT, int ksplit) {
  int bf = *dflag;
  int tA = rt(tAc, bf), tB = rt(tBc, bf), tC = rt(tCc, bf);
  int bz = blockIdx.z, ks = 0;
  if (ksplit > 1) { bz = blockIdx.z / ksplit; ks = blockIdx.z - bz * ksplit; }
  int Kc = K / ksplit;
  int kbeg = ks * Kc, kend = kbeg + Kc;
  long baseA = (long)bz * sA;
  long baseC = (long)bz * sC + oC;
  int m0 = blockIdx.y * 64, n0 = blockIdx.x * 128;
  int tid = threadIdx.x;
  int wave = tid >> 6, lane = tid & 63;
  int wm = wave >> 1, wn = wave & 1;
  int quad = lane >> 4, l16 = lane & 15;

  __shared__ __align__(16) short As[64][40];
  __shared__ __align__(16) short Bs[128][40];

  floatx4 acc[2][4];
  #pragma unroll
  for (int i = 0; i < 2; ++i)
    #pragma unroll
    for (int j = 0; j < 4; ++j) acc[i][j] = floatx4{0.f, 0.f, 0.f, 0.f};

  int am_ = tid >> 2;
  int ak  = (tid & 3) * 8;
  int bk2 = tid >> 4;
  int bnc = tid & 15;
  int bcol = n0 + bnc * 8;
  if (bcol + 8 > N) bcol = N - 8;
  long cbO = (long)bz * sB + oB + bcol;
  int bn_ = tid & 127;
  int bkc = (tid >> 7) * 16;
  int brow = n0 + bn_; if (brow >= N) brow = N - 1;

  auto loadA = [&](int kx, short8& v) {
    long src = baseA + (long)(m0 + am_) * lda + kx + ak;
    if (tA) v = *(const short8*)((const short*)A + src);
    else {
      const float* f = (const float*)A + src;
      floatx4 f0 = *(const floatx4*)f, f1 = *(const floatx4*)(f + 4);
      v[0]=f2bs(f0[0]); v[1]=f2bs(f0[1]); v[2]=f2bs(f0[2]); v[3]=f2bs(f0[3]);
      v[4]=f2bs(f1[0]); v[5]=f2bs(f1[1]); v[6]=f2bs(f1[2]); v[7]=f2bs(f1[3]);
    }
  };
  auto loadBold = [&](int krow, short8& v) {
    if (tB) v = *(const short8*)((const short*)Bm + (long)krow * ldb + cbO);
    else {
      const float* f = (const float*)Bm + (long)krow * ldb + cbO;
      floatx4 f0 = *(const floatx4*)f, f1 = *(const floatx4*)(f + 4);
      v[0]=f2bs(f0[0]); v[1]=f2bs(f0[1]); v[2]=f2bs(f0[2]); v[3]=f2bs(f0[3]);
      v[4]=f2bs(f1[0]); v[5]=f2bs(f1[1]); v[6]=f2bs(f1[2]); v[7]=f2bs(f1[3]);
    }
  };
  auto loadBT = [&](int kx, short8& v0, short8& v1) {
    const short* p = (const short*)Bm + (long)brow * ldb + kx + bkc;
    v0 = *(const short8*)p;
    v1 = *(const short8*)(p + 8);
  };

  short8 vA, vB0, vB1;
  loadA(kbeg, vA);
  if (tBT) loadBT(kbeg, vB0, vB1);
  else { loadBold(kbeg + bk2, vB0); loadBold(kbeg + bk2 + 16, vB1); }

  for (int k0 = kbeg; k0 < kend; k0 += 32) {
    if (k0 != kbeg) __syncthreads();
    *(short8*)&As[am_][ak] = vA;
    if (tBT) {
      *(short8*)&Bs[bn_][bkc]     = vB0;
      *(short8*)&Bs[bn_][bkc + 8] = vB1;
    } else {
      #pragma unroll
      for (int j = 0; j < 8; ++j) {
        Bs[bnc * 8 + j][bk2]      = vB0[j];
        Bs[bnc * 8 + j][bk2 + 16] = vB1[j];
      }
    }
    __syncthreads();
    int kn = k0 + 32;
    if (kn < kend) {
      loadA(kn, vA);
      if (tBT) loadBT(kn, vB0, vB1);
      else { loadBold(kn + bk2, vB0); loadBold(kn + bk2 + 16, vB1); }
    }
    short8 af[2], bfr[4];
    #pragma unroll
    for (int i = 0; i < 2; ++i)
      af[i] = *(const short8*)&As[wm * 32 + i * 16 + l16][quad * 8];
    #pragma unroll
    for (int j = 0; j < 4; ++j)
      bfr[j] = *(const short8*)&Bs[wn * 64 + j * 16 + l16][quad * 8];
    #pragma unroll
    for (int i = 0; i < 2; ++i)
      #pragma unroll
      for (int j = 0; j < 4; ++j)
        acc[i][j] = __builtin_amdgcn_mfma_f32_16x16x32_bf16(af[i], bfr[j], acc[i][j], 0, 0, 0);
  }

  #pragma unroll
  for (int i = 0; i < 2; ++i) {
    int m = m0 + wm * 32 + i * 16 + quad * 4;
    #pragma unroll
    for (int j = 0; j < 4; ++j) {
      int n = n0 + wn * 64 + j * 16 + l16;
      if (n >= N) continue;
      float bn_add = 0.f;
      if ((flags & 1) && ks == 0) {
        bn_add = (bias2 != nullptr && n >= Nsplit) ? ldt(bias2, n - Nsplit, tB)
                                                   : ldt(bias, oBias + n, tB);
      }
      #pragma unroll
      for (int r = 0; r < 4; ++r) {
        float v = acc[i][j][r] + bn_add;
        if ((flags & 2) && ks == 0) v += ldt(bias, oBias + m + r, tB);
        long off = baseC + (long)(m + r) * ldc + n;
        if (ksplit > 1) {
          atomicAdd((float*)C + off, v);
        } else {
          if (flags & 8) v += ldt(C, off, tC);
          if (flags & 4) v = fmaxf(v, 0.f);
          stt(C, off, tC, v);
        }
      }
    }
  }
}

// ---------------- encoder GEMM v2: K=256 resident A-tile, B fragments direct from L2 ----------------
// do_sm=1: softmax over each 16-col group for n >= Nsplit (fused attention-weight softmax).
__global__ __launch_bounds__(256) void egemm_kernel(const int* __restrict__ dflag,
    const void* __restrict__ A, const short* __restrict__ Bt,
    const void* __restrict__ bias, const void* __restrict__ bias2, void* __restrict__ C,
    int N, int ldc, int Nsplit, int tAc, int tCc, int do_sm) {
  int bf = *dflag;
  int tA = rt(tAc, bf), tC = rt(tCc, bf);
  int m0 = blockIdx.y * 64, n0 = blockIdx.x * 128;
  int tid = threadIdx.x;
  int wave = tid >> 6, lane = tid & 63;
  int wm = wave >> 1, wn = wave & 1;
  int quad = lane >> 4, l16 = lane & 15;

  __shared__ __align__(16) short As[64][264];

  floatx4 acc[2][4];
  #pragma unroll
  for (int i = 0; i < 2; ++i)
    #pragma unroll
    for (int j = 0; j < 4; ++j) acc[i][j] = floatx4{0.f, 0.f, 0.f, 0.f};

  // stage full A tile (64 x 256) once
  {
    int r = tid >> 2, c0 = (tid & 3) * 64;
    if (tA) {
      const short* s = (const short*)A + (long)(m0 + r) * 256 + c0;
      #pragma unroll
      for (int c = 0; c < 64; c += 8)
        *(short8*)&As[r][c0 + c] = *(const short8*)(s + c);
    } else {
      const float* f = (const float*)A + (long)(m0 + r) * 256 + c0;
      #pragma unroll
      for (int c = 0; c < 64; c += 8) {
        floatx4 f0 = *(const floatx4*)(f + c);
        floatx4 f1 = *(const floatx4*)(f + c + 4);
        short8 v;
        v[0]=f2bs(f0[0]); v[1]=f2bs(f0[1]); v[2]=f2bs(f0[2]); v[3]=f2bs(f0[3]);
        v[4]=f2bs(f1[0]); v[5]=f2bs(f1[1]); v[6]=f2bs(f1[2]); v[7]=f2bs(f1[3]);
        *(short8*)&As[r][c0 + c] = v;
      }
    }
  }
  __syncthreads();

  // barrier-free K loop; B fragments straight from L2
  #pragma unroll
  for (int k0 = 0; k0 < 256; k0 += 32) {
    short8 af[2], bfr[4];
    #pragma unroll
    for (int j = 0; j < 4; ++j)
      bfr[j] = *(const short8*)(Bt + (long)(n0 + wn * 64 + j * 16 + l16) * 256 + k0 + quad * 8);
    #pragma unroll
    for (int i = 0; i < 2; ++i)
      af[i] = *(const short8*)&As[wm * 32 + i * 16 + l16][k0 + quad * 8];
    #pragma unroll
    for (int i = 0; i < 2; ++i)
      #pragma unroll
      for (int j = 0; j < 4; ++j)
        acc[i][j] = __builtin_amdgcn_mfma_f32_16x16x32_bf16(af[i], bfr[j], acc[i][j], 0, 0, 0);
  }

  #pragma unroll
  for (int i = 0; i < 2; ++i) {
    int m = m0 + wm * 32 + i * 16 + quad * 4;
    #pragma unroll
    for (int j = 0; j < 4; ++j) {
      int n = n0 + wn * 64 + j * 16 + l16;
      if (n >= N) continue;
      float bn_add = (bias2 != nullptr && n >= Nsplit) ? ldt(bias2, n - Nsplit, bf)
                                                       : ldt(bias, n, bf);
      float vv[4];
      #pragma unroll
      for (int r = 0; r < 4; ++r) vv[r] = acc[i][j][r] + bn_add;
      if (do_sm && n0 + wn * 64 + j * 16 >= Nsplit) {
        #pragma unroll
        for (int r = 0; r < 4; ++r) {
          float x = vv[r];
          float mx = x;
          #pragma unroll
          for (int msk = 1; msk < 16; msk <<= 1)
            mx = fmaxf(mx, __shfl_xor(mx, msk));
          float e = expf(x - mx);
          float ssum = e;
          #pragma unroll
          for (int msk = 1; msk < 16; msk <<= 1)
            ssum += __shfl_xor(ssum, msk);
          vv[r] = e / ssum;
        }
      }
      #pragma unroll
      for (int r = 0; r < 4; ++r)
        stt(C, (long)(m + r) * ldc + n, tC, vv[r]);
    }
  }
}

// ---------------- fused FFN v6: weights via async global_load_lds, triple-buffered ----------------
// out = relu(src@W1 + b1) @ W2 + b2. W1t [2048][256], W2t [256][2048].
// Each 32-K step stages a [128 n][32 k] weight tile (8 KB) into LDS with
// global_load_lds (coalesced per-lane sources), prefetching the next step
// before the barrier. Triple buffer makes one barrier per step safe.
__global__ __launch_bounds__(256) void ffn_kernel(const int* __restrict__ dflag,
    const float* __restrict__ src, const short* __restrict__ W1t, const void* __restrict__ b1,
    const short* __restrict__ W2t, const void* __restrict__ b2, bf16* __restrict__ out) {
  int bf = *dflag;
  long m0 = (long)blockIdx.x * 32;
  int tid = threadIdx.x;
  int wn = tid >> 6, lane = tid & 63;
  int quad = lane >> 4, l16 = lane & 15;

  __shared__ __align__(16) short As[32][264];   // src tile, K=256 resident
  __shared__ __align__(16) short Hs[32][136];   // hidden chunk (128 k)
  __shared__ __align__(16) short Bs3[3][4096];  // weight tile buffers [128][32]

  // per-lane staging map: n = slot*16 + lane/4, k = (lane&3)*8, slot = wn*2 + t
  int sn = lane >> 2, sk = (lane & 3) * 8;

  floatx4 acc2[2][4];
  #pragma unroll
  for (int i = 0; i < 2; ++i)
    #pragma unroll
    for (int j = 0; j < 4; ++j) acc2[i][j] = floatx4{0.f, 0.f, 0.f, 0.f};

  // stage src tile once (32 x 256)
  {
    int r = tid >> 3, c0 = (tid & 7) * 32;
    const float* sp = src + (m0 + r) * 256 + c0;
    #pragma unroll
    for (int c = 0; c < 32; c += 8) {
      floatx4 f0 = *(const floatx4*)(sp + c);
      floatx4 f1 = *(const floatx4*)(sp + c + 4);
      short8 v;
      v[0]=f2bs(f0[0]); v[1]=f2bs(f0[1]); v[2]=f2bs(f0[2]); v[3]=f2bs(f0[3]);
      v[4]=f2bs(f1[0]); v[5]=f2bs(f1[1]); v[6]=f2bs(f1[2]); v[7]=f2bs(f1[3]);
      *(short8*)&As[r][c0 + c] = v;
    }
  }

  auto stageW1 = [&](int buf, int ch, int k1) {
    #pragma unroll
    for (int t = 0; t < 2; ++t) {
      int slot = wn * 2 + t;
      int n = slot * 16 + sn;
      const short* gp = W1t + (long)(ch * 128 + n) * 256 + k1 + sk;
      gload_lds16(gp, &Bs3[buf][slot * 512]);
    }
  };
  auto stageW2 = [&](int buf, int ch, int t2) {
    int nh = t2 >> 2, k2 = (t2 & 3) * 32;
    #pragma unroll
    for (int t = 0; t < 2; ++t) {
      int slot = wn * 2 + t;
      int n = slot * 16 + sn;
      const short* gp = W2t + (long)(nh * 128 + n) * 2048 + ch * 128 + k2 + sk;
      gload_lds16(gp, &Bs3[buf][slot * 512]);
    }
  };

  __syncthreads();   // As visible

  for (int ch = 0; ch < 16; ++ch) {
    floatx4 acc1[2][2];
    #pragma unroll
    for (int i = 0; i < 2; ++i)
      #pragma unroll
      for (int j = 0; j < 2; ++j) acc1[i][j] = floatx4{0.f, 0.f, 0.f, 0.f};

    // ---- stage1: H = relu(src @ W1chunk) ----
    stageW1(0, ch, 0);
    #pragma unroll
    for (int s = 0; s < 8; ++s) {
      if (s < 7) stageW1((s + 1) % 3, ch, (s + 1) * 32);
      __syncthreads();   // drains loads; buf[s%3] ready
      const short* bb = &Bs3[s % 3][0];
      short8 af[2], bfr[2];
      #pragma unroll
      for (int j = 0; j < 2; ++j)
        bfr[j] = *(const short8*)(bb + (wn * 32 + j * 16 + l16) * 32 + quad * 8);
      #pragma unroll
      for (int i = 0; i < 2; ++i)
        af[i] = *(const short8*)&As[i * 16 + l16][s * 32 + quad * 8];
      #pragma unroll
      for (int i = 0; i < 2; ++i)
        #pragma unroll
        for (int j = 0; j < 2; ++j)
          acc1[i][j] = __builtin_amdgcn_mfma_f32_16x16x32_bf16(af[i], bfr[j], acc1[i][j], 0, 0, 0);
    }

    __syncthreads();   // all stage1 reads done (also guards Hs overwrite)
    #pragma unroll
    for (int i = 0; i < 2; ++i)
      #pragma unroll
      for (int j = 0; j < 2; ++j) {
        int nl = wn * 32 + j * 16 + l16;
        float bb = ldt(b1, (long)ch * 128 + nl, bf);
        #pragma unroll
        for (int r = 0; r < 4; ++r) {
          float hv = fmaxf(acc1[i][j][r] + bb, 0.f);
          Hs[i * 16 + quad * 4 + r][nl] = f2bs(hv);
        }
      }
    stageW2(0, ch, 0);   // prefetch first stage2 tile (buf0 reads finished at s=6<7)
    __syncthreads();     // Hs visible + stage2 buf0 ready

    // ---- stage2: acc2 += H @ W2chunk ----
    #pragma unroll
    for (int s = 0; s < 8; ++s) {
      if (s < 7) stageW2((s + 1) % 3, ch, s + 1);
      if (s) __syncthreads();
      int nh = s >> 2;
      const short* bb = &Bs3[s % 3][0];
      short8 ah[2], bfr[2];
      #pragma unroll
      for (int j = 0; j < 2; ++j)
        bfr[j] = *(const short8*)(bb + (wn * 32 + j * 16 + l16) * 32 + quad * 8);
      int k2 = (s & 3) * 32;
      #pragma unroll
      for (int i = 0; i < 2; ++i)
        ah[i] = *(const short8*)&Hs[i * 16 + l16][k2 + quad * 8];
      #pragma unroll
      for (int i = 0; i < 2; ++i)
        #pragma unroll
        for (int j = 0; j < 2; ++j)
          acc2[i][nh * 2 + j] =
              __builtin_amdgcn_mfma_f32_16x16x32_bf16(ah[i], bfr[j], acc2[i][nh * 2 + j], 0, 0, 0);
    }
    __syncthreads();   // all stage2 reads done before next chunk's staging
  }

  #pragma unroll
  for (int i = 0; i < 2; ++i) {
    long m = m0 + i * 16 + quad * 4;
    #pragma unroll
    for (int nh = 0; nh < 2; ++nh)
      #pragma unroll
      for (int j = 0; j < 2; ++j) {
        int n = nh * 128 + wn * 32 + j * 16 + l16;
        float bb = ldt(b2, n, bf);
        #pragma unroll
        for (int r = 0; r < 4; ++r)
          out[(m + r) * 256 + n] = __float2bfloat16(acc2[i][nh * 2 + j][r] + bb);
      }
  }
}

// ---------------- 3x3 conv as MFMA implicit GEMM (pre-transposed bf16 weights) ----------------
__global__ __launch_bounds__(256) void mconv_kernel(const short* __restrict__ Wc,
    const float* __restrict__ X, float* __restrict__ Y, int H, int Wd, int lw) {
  int bz = blockIdx.z;
  int HW = H * Wd;
  const float* Xb = X + (long)bz * 256 * HW;
  float* Yb = Y + (long)bz * 256 * HW;
  int m0 = blockIdx.y * 64, n0 = blockIdx.x * 128;
  int tid = threadIdx.x;
  int wave = tid >> 6, lane = tid & 63;
  int wm = wave >> 1, wn = wave & 1;
  int quad = lane >> 4, l16 = lane & 15;

  __shared__ __align__(16) short As[64][40];
  __shared__ __align__(16) short Bs[128][40];

  floatx4 acc[2][4];
  #pragma unroll
  for (int i = 0; i < 2; ++i)
    #pragma unroll
    for (int j = 0; j < 4; ++j) acc[i][j] = floatx4{0.f, 0.f, 0.f, 0.f};

  int am_ = tid >> 2;
  int ak  = (tid & 3) * 8;
  int bn_ = tid & 127;
  int bkc = (tid >> 7) * 16;
  int gn  = n0 + bn_; if (gn >= HW) gn = HW - 1;
  int y = gn >> lw, x = gn & (Wd - 1);

  const short* Arow = Wc + (long)(m0 + am_) * 2304 + ak;

  short8 vA;
  float rB[16];
  auto pre = [&](int k0) {
    vA = *(const short8*)(Arow + k0);
    int tap = k0 >> 8;
    int dy = tap / 3 - 1, dx = tap % 3 - 1;
    bool ok = ((unsigned)(y + dy) < (unsigned)H) && ((unsigned)(x + dx) < (unsigned)Wd);
    const float* xp = Xb + (long)((k0 & 255) + bkc) * HW + gn + dy * Wd + dx;
    #pragma unroll
    for (int j = 0; j < 16; ++j)
      rB[j] = ok ? xp[(long)j * HW] : 0.f;
  };

  pre(0);
  for (int k0 = 0; k0 < 2304; k0 += 32) {
    if (k0) __syncthreads();
    *(short8*)&As[am_][ak] = vA;
    #pragma unroll
    for (int j = 0; j < 16; ++j) Bs[bn_][bkc + j] = f2bs(rB[j]);
    __syncthreads();
    if (k0 + 32 < 2304) pre(k0 + 32);
    short8 af[2], bfr[4];
    #pragma unroll
    for (int i = 0; i < 2; ++i)
      af[i] = *(const short8*)&As[wm * 32 + i * 16 + l16][quad * 8];
    #pragma unroll
    for (int j = 0; j < 4; ++j)
      bfr[j] = *(const short8*)&Bs[wn * 64 + j * 16 + l16][quad * 8];
    #pragma unroll
    for (int i = 0; i < 2; ++i)
      #pragma unroll
      for (int j = 0; j < 4; ++j)
        acc[i][j] = __builtin_amdgcn_mfma_f32_16x16x32_bf16(af[i], bfr[j], acc[i][j], 0, 0, 0);
  }

  #pragma unroll
  for (int i = 0; i < 2; ++i) {
    int m = m0 + wm * 32 + i * 16 + quad * 4;
    #pragma unroll
    for (int j = 0; j < 4; ++j) {
      int n = n0 + wn * 64 + j * 16 + l16;
      if (n >= HW) continue;
      #pragma unroll
      for (int r = 0; r < 4; ++r)
        Yb[(long)(m + r) * HW + n] = acc[i][j][r];
    }
  }
}

// ---------------- GroupNorm in-place (fp32 X) ----------------
__global__ __launch_bounds__(256) void gn_kernel(const int* __restrict__ dflag,
    float* __restrict__ X, const void* __restrict__ gs, const void* __restrict__ gb,
    long po, int HW, int relu) {
  int bf = *dflag;
  int g = blockIdx.x, b = blockIdx.y;
  float* base = X + ((long)b * 256 + g * 8) * HW;
  int n = 8 * HW;
  int t = threadIdx.x;
  float s1 = 0.f, s2 = 0.f;
  for (int i = t; i < n; i += 256) { float v = base[i]; s1 += v; s2 += v * v; }
  __shared__ float r1[256], r2[256];
  r1[t] = s1; r2[t] = s2; __syncthreads();
  for (int sh = 128; sh > 0; sh >>= 1) {
    if (t < sh) { r1[t] += r1[t + sh]; r2[t] += r2[t + sh]; }
    __syncthreads();
  }
  float mu = r1[0] / n;
  float var = fmaxf(r2[0] / n - mu * mu, 0.f);
  float inv = rsqrtf(var + 1e-5f);
  for (int i = t; i < n; i += 256) {
    int c = g * 8 + i / HW;
    float v = (base[i] - mu) * inv * ldt(gs, po + c, bf) + ldt(gb, po + c, bf);
    if (relu) v = fmaxf(v, 0.f);
    base[i] = v;
  }
}

// ---------------- bilinear 0.5x downsample (2x2 avg) added into target ----------------
__global__ __launch_bounds__(256) void dsadd_kernel(float* __restrict__ T,
    const float* __restrict__ P, int H, int Wd) {
  int idx = blockIdx.x * 256 + threadIdx.x;
  int total = BB * 256 * H * Wd;
  if (idx >= total) return;
  int x = idx % Wd, y = (idx / Wd) % H;
  int bc = idx / (Wd * H);
  const float* Pp = P + (((long)bc * (2 * H) + 2 * y) * (2 * Wd) + 2 * x);
  T[idx] += 0.25f * (Pp[0] + Pp[1] + Pp[2 * Wd] + Pp[2 * Wd + 1]);
}

// ---------------- build src (fp32) from FPN maps ----------------
__global__ __launch_bounds__(256) void srcbuild_kernel(const float* __restrict__ O0,
    const float* __restrict__ O1, const float* __restrict__ O2, const float* __restrict__ O3,
    float* __restrict__ src) {
  int idx = blockIdx.x * 256 + threadIdx.x;
  if (idx >= MTOT * 256) return;
  int c = idx & 255;
  int bs = idx >> 8;
  int s = bs % S_TOT, b = bs / S_TOT;
  int st, w, h; lvl_of(s, st, w, h);
  const float* O = (s < 4096) ? O0 : (s < 5120) ? O1 : (s < 5376) ? O2 : O3;
  int HW = w * h;
  src[idx] = O[((long)(b * 256 + c)) * HW + (s - st)];
}

// ---------------- layer-0 q = bf16(src + pos) ----------------
__global__ __launch_bounds__(256) void qinit_kernel(const float* __restrict__ src,
    bf16* __restrict__ q) {
  int idx = blockIdx.x * 256 + threadIdx.x;
  if (idx >= MTOT * 256) return;
  int c = idx & 255;
  int bs = idx >> 8;
  int s = bs % S_TOT;
  q[idx] = __float2bfloat16(src[idx] + pos_enc(s, c));
}

// ---------------- multi-scale deformable sampling (fused off|aw layout) ----------------
__global__ __launch_bounds__(256) void deform_kernel(const bf16* __restrict__ value,
    const bf16* __restrict__ oaw, bf16* __restrict__ attn) {
  int idx = blockIdx.x * 256 + threadIdx.x;
  if (idx >= MTOT * 256) return;
  int d = idx & 31;
  int h = (idx >> 5) & 7;
  int bs = idx >> 8;
  int s = bs % S_TOT, b = bs / S_TOT;
  int stS, wS, hS; lvl_of(s, stS, wS, hS);
  int pl = s - stS;
  float rx = ((pl % wS) + 0.5f) / wS;
  float ry = ((pl / wS) + 0.5f) / hS;
  const bf16* offr = oaw + (long)bs * 384 + h * 32;
  const bf16* awr  = oaw + (long)bs * 384 + 256 + h * 16;
  const bf16* vbase = value + (long)b * S_TOT * 256 + h * 32 + d;
  const int LW[4] = {64, 32, 16, 8}, LST[4] = {0, 4096, 5120, 5376};
  float acc = 0.f;
  #pragma unroll
  for (int l = 0; l < 4; ++l) {
    int w = LW[l], hh = LW[l], st = LST[l];
    #pragma unroll
    for (int p = 0; p < 4; ++p) {
      float ox = __bfloat162float(offr[l * 8 + p * 2 + 0]);
      float oy = __bfloat162float(offr[l * 8 + p * 2 + 1]);
      float x = rx * w + ox - 0.5f;
      float y = ry * hh + oy - 0.5f;
      float x0f = floorf(x), y0f = floorf(y);
      int x0 = (int)x0f, y0 = (int)y0f;
      float fx = x - x0f, fy = y - y0f;
      float a = __bfloat162float(awr[l * 4 + p]);
      float sample = 0.f;
      #pragma unroll
      for (int ty2 = 0; ty2 < 2; ++ty2) {
        int yi = y0 + ty2;
        float wy = ty2 ? fy : 1.f - fy;
        bool vy = (yi >= 0) && (yi < hh);
        int yc = min(max(yi, 0), hh - 1);
        #pragma unroll
        for (int tx2 = 0; tx2 < 2; ++tx2) {
          int xi = x0 + tx2;
          float wx = tx2 ? fx : 1.f - fx;
          bool vx = (xi >= 0) && (xi < w);
          int xc = min(max(xi, 0), w - 1);
          float v = __bfloat162float(vbase[(long)(st + yc * w + xc) * 256]);
          if (vx && vy) sample += wy * wx * v;
        }
      }
      acc += a * sample;
    }
  }
  attn[idx] = __float2bfloat16(acc);
}

// ---------------- LayerNorm(src + resid_bf16), wave-per-row, optional q = bf16(out + pos) ----------------
__global__ __launch_bounds__(256) void ln_kernel(const int* __restrict__ dflag,
    float* __restrict__ src, const bf16* __restrict__ resid,
    const void* __restrict__ g, const void* __restrict__ b, bf16* __restrict__ qout) {
  int bf = *dflag;
  long r = (long)blockIdx.x * 4 + (threadIdx.x >> 6);
  int lane = threadIdx.x & 63;
  float* x = src + r * 256;
  const bf16* a = resid + r * 256;
  float v[4];
  float s1 = 0.f, s2 = 0.f;
  #pragma unroll
  for (int k = 0; k < 4; ++k) {
    int c = lane + 64 * k;
    float t = x[c] + __bfloat162float(a[c]);
    v[k] = t; s1 += t; s2 += t * t;
  }
  #pragma unroll
  for (int msk = 1; msk < 64; msk <<= 1) {
    s1 += __shfl_xor(s1, msk);
    s2 += __shfl_xor(s2, msk);
  }
  float mu = s1 * (1.f / 256.f);
  float var = fmaxf(s2 * (1.f / 256.f) - mu * mu, 0.f);
  float inv = rsqrtf(var + 1e-5f);
  int s = (int)(r % S_TOT);
  #pragma unroll
  for (int k = 0; k < 4; ++k) {
    int c = lane + 64 * k;
    float o = (v[k] - mu) * inv * ldt(g, c, bf) + ldt(b, c, bf);
    x[c] = o;
    if (qout) qout[r * 256 + c] = __float2bfloat16(o + pos_enc(s, c));
  }
}

// ---------------- unflatten src -> out chunks 1..4 ----------------
__global__ __launch_bounds__(256) void unflat_kernel(const int* __restrict__ dflag,
    const float* __restrict__ src, void* __restrict__ out) {
  int bf = *dflag;
  int idx = blockIdx.x * 256 + threadIdx.x;
  if (idx >= MTOT * 256) return;
  int c = idx & 255;
  int bs = idx >> 8;
  int s = bs % S_TOT, b = bs / S_TOT;
  int st, w, h; lvl_of(s, st, w, h);
  int HW = w * h;
  long base = (s < 4096) ? 2097152L : (s < 5120) ? 4194304L : (s < 5376) ? 4718592L : 4849664L;
  stt(out, base + ((long)(b * 256 + c)) * HW + (s - st), bf, src[idx]);
}

// ---------------- sentinel ----------------
__global__ __launch_bounds__(256) void sentinel_kernel(float* __restrict__ out, int n) {
  int i = blockIdx.x * 256 + threadIdx.x;
  if (i < n) out[i] = 999.0f;
}

// =====================================================================
extern "C" void kernel_launch(void* const* d_in, const int* in_sizes, int n_in,
                              void* d_out, int out_size, void* d_ws, size_t ws_size,
                              hipStream_t stream) {
  (void)in_sizes; (void)n_in;
  // 7,659,520 activations + 64 flag + 638,976 transposed-weight floats
  const size_t NEED = (7659520ull + 64ull + 638976ull) * 4ull;
  if (ws_size < NEED) {
    int nf = out_size / 2;
    sentinel_kernel<<<(nf + 255) / 256, 256, 0, stream>>>((float*)d_out, nf);
    return;
  }

  const void* feat[4] = {d_in[0], d_in[1], d_in[2], d_in[3]};
  const void* latw[4] = {d_in[4], d_in[5], d_in[6], d_in[7]};
  const void *latgns = d_in[8], *latgnb = d_in[9];
  const void* outw = d_in[10];
  const void *outgns = d_in[11], *outgnb = d_in[12];
  const void *offw = d_in[13], *offb_ = d_in[14], *aww = d_in[15], *awb_ = d_in[16];
  const void *valw = d_in[17], *valb_ = d_in[18], *projw = d_in[19], *projb_ = d_in[20];
  const void *f1w = d_in[21], *f1b = d_in[22], *f2w = d_in[23], *f2b = d_in[24];
  const void *ln1s = d_in[25], *ln1b = d_in[26], *ln2s = d_in[27], *ln2b = d_in[28];
  const void *maskw = d_in[29], *maskb = d_in[30];

  float* W = (float*)d_ws;
  float* srcb  = W;
  float* fpn_a = W;
  bf16*  oawbf = (bf16*)(W + 2785280);
  bf16*  tmpbf = oawbf;
  bf16*  qbf   = (bf16*)(W + 4874240);
  bf16*  valbf = (bf16*)(W + 6266880);
  float* ObF   = W + 4874240;
  float* Ob[4] = {ObF, ObF + 2097152, ObF + 2621440, ObF + 2752512};
  int*   dflag = (int*)(W + 7659520);
  short* wtS   = (short*)(W + 7659584);
  short* valt  = wtS;             // [256][256]
  short* projt = wtS + 65536;     // [256][256]
  short* oawt  = wtS + 131072;    // [384][256]
  short* w1t   = wtS + 229376;    // [2048][256]
  short* w2t   = wtS + 753664;    // [256][2048]
  // conv weights (bf16, [4][256][2304]) live in the encoder-phase oawbf region;
  // FPN finishes before the encoder overwrites it.
  short* wconvt = (short*)(W + 2785280);   // 2,359,296 shorts, ends at W+3964928

  detect_kernel<<<1, 1, 0, stream>>>(ln1s, dflag);
  // pre-transpose encoder weights to bf16 [N][K]
  wtrans_kernel<<<(65536 + 255) / 256, 256, 0, stream>>>(dflag, valw, valt, 256, 256);
  wtrans_kernel<<<(65536 + 255) / 256, 256, 0, stream>>>(dflag, projw, projt, 256, 256);
  wtrans_kernel<<<(65536 + 255) / 256, 256, 0, stream>>>(dflag, offw, oawt, 256, 256);
  wtrans_kernel<<<(32768 + 255) / 256, 256, 0, stream>>>(dflag, aww, oawt + 65536, 256, 128);
  wtrans_kernel<<<(524288 + 255) / 256, 256, 0, stream>>>(dflag, f1w, w1t, 256, 2048);
  wtrans_kernel<<<(524288 + 255) / 256, 256, 0, stream>>>(dflag, f2w, w2t, 2048, 256);
  wconvt_kernel<<<(2359296 + 255) / 256, 256, 0, stream>>>(dflag, outw, wconvt);

  const int M = MTOT;
  auto mgemm = [&](const void* A, const void* B, const void* bias, const void* bias2,
                   void* C, int Mi, int Ni, int Ki, int lda, int ldb, int ldc, int Nsplit,
                   long sA, long sB, long sC, long oB, long oBias, long oC,
                   int batch, int flags, int tA, int tB, int tC, int tBT, int ksplit) {
    dim3 g((Ni + 127) / 128, Mi / 64, batch * ksplit);
    mgemm_kernel<<<g, 256, 0, stream>>>(dflag, A, B, bias, bias2, C, Mi, Ni, Ki,
                                        lda, ldb, ldc, Nsplit,
                                        sA, sB, sC, oB, oBias, oC, flags, tA, tB, tC, tBT,
                                        ksplit);
  };
  auto egemm = [&](const void* A, const short* Bt, const void* bias, const void* bias2,
                   void* C, int Ni, int ldc, int Nsplit, int tA, int tC, int do_sm) {
    dim3 g((Ni + 127) / 128, M / 64, 1);
    egemm_kernel<<<g, 256, 0, stream>>>(dflag, A, Bt, bias, bias2, C, Ni, ldc, Nsplit,
                                        tA, tC, do_sm);
  };

  // ---------------- FPN ----------------
  const int LVL[4] = {64, 32, 16, 8};
  const int LGW[4] = {6, 5, 4, 3};
  const int CIN[4] = {256, 512, 1024, 2048};
  const int KSP[4] = {1, 4, 8, 16};   // split-K for under-parallelized laterals
  for (int i = 0; i < 4; ++i) {
    int H = LVL[i], HW = H * H, Cin = CIN[i];
    int ksp = KSP[i];
    if (ksp > 1)
      zero_kernel<<<(BB * 256 * HW + 255) / 256, 256, 0, stream>>>(fpn_a, BB * 256 * HW);
    mgemm(latw[i], feat[i], nullptr, nullptr, fpn_a, 256, HW, Cin,
          Cin, HW, HW, 0, 0, (long)Cin * HW, (long)256 * HW, 0, 0, 0, BB, 0, 2, 2, 0, 0, ksp);
    gn_kernel<<<dim3(32, BB), 256, 0, stream>>>(dflag, fpn_a, latgns, latgnb,
                                                (long)i * 256, HW, 0);
    if (i > 0) {
      int total = BB * 256 * HW;
      dsadd_kernel<<<(total + 255) / 256, 256, 0, stream>>>(fpn_a, Ob[i - 1], H, H);
    }
    {
      dim3 g((HW + 127) / 128, 4, BB);
      mconv_kernel<<<g, 256, 0, stream>>>(wconvt + (long)i * 589824, fpn_a, Ob[i],
                                          H, H, LGW[i]);
    }
    gn_kernel<<<dim3(32, BB), 256, 0, stream>>>(dflag, Ob[i], outgns, outgnb,
                                                (long)i * 256, HW, 1);
  }

  srcbuild_kernel<<<(M * 256) / 256, 256, 0, stream>>>(Ob[0], Ob[1], Ob[2], Ob[3], srcb);
  // layer-0 q (runs after srcbuild fully consumed Ob; qbf aliases Ob[0] safely now)
  qinit_kernel<<<(M * 256) / 256, 256, 0, stream>>>(srcb, qbf);

  // ---------------- encoder layers (shared weights) ----------------
  for (int L = 0; L < 6; ++L) {
    egemm(srcb, valt, valb_, nullptr, valbf, 256, 256, 256, 0, 1, 0);
    egemm(qbf, oawt, offb_, awb_, oawbf, 384, 384, 256, 1, 1, 1);   // fused aw softmax
    deform_kernel<<<(M * 256) / 256, 256, 0, stream>>>(valbf, oawbf, qbf);
    egemm(qbf, projt, projb_, nullptr, tmpbf, 256, 256, 256, 1, 1, 0);
    ln_kernel<<<M / 4, 256, 0, stream>>>(dflag, srcb, tmpbf, ln1s, ln1b, nullptr);
    ffn_kernel<<<M / 32, 256, 0, stream>>>(dflag, srcb, w1t, f1b, w2t, f2b, tmpbf);
    ln_kernel<<<M / 4, 256, 0, stream>>>(dflag, srcb, tmpbf, ln2s, ln2b,
                                         (L < 5) ? qbf : nullptr);
  }

  // ---------------- outputs ----------------
  unflat_kernel<<<(M * 256) / 256, 256, 0, stream>>>(dflag, srcb, d_out);
  mgemm(maskw, d_out, maskb, nullptr, d_out, 256, 4096, 256,
        256, 4096, 4096, 0, 0, 1048576L, 1048576L, 2097152L, 0, 0, BB, 2, 2, 2, 2, 0, 1);
}

// Round 15
// 1826.680 us; speedup vs baseline: 1.3330x; 1.2463x over previous
//
#include <hip/hip_runtime.h>
#include <hip/hip_bf16.h>

typedef __hip_bfloat16 bf16;
typedef __attribute__((ext_vector_type(8))) short short8;
typedef __attribute__((ext_vector_type(4))) short short4v;
typedef __attribute__((ext_vector_type(4))) float floatx4;

#define S_TOT 5440
#define BB 2
#define MTOT (BB * S_TOT)  // 10880

__device__ __forceinline__ float ldt(const void* p, long i, int t) {
  return t ? __bfloat162float(((const bf16*)p)[i]) : ((const float*)p)[i];
}
__device__ __forceinline__ void stt(void* p, long i, int t, float v) {
  if (t) ((bf16*)p)[i] = __float2bfloat16(v);
  else   ((float*)p)[i] = v;
}
__device__ __forceinline__ int rt(int code, int bf) { return code == 2 ? bf : code; }
__device__ __forceinline__ short f2bs(float f) {
  bf16 h = __float2bfloat16(f);
  return *(short*)&h;
}
__device__ __forceinline__ float bs2f(short s) {
  bf16 h = *(bf16*)&s;
  return __bfloat162float(h);
}
__device__ __forceinline__ short ldbs(const void* p, long i, int t) {
  return t ? ((const short*)p)[i] : f2bs(((const float*)p)[i]);
}

// async global->LDS 16B per lane (dest = ldsbase + lane*16)
__device__ __forceinline__ void gload_lds16(const short* g, short* l) {
  __builtin_amdgcn_global_load_lds(
      (const __attribute__((address_space(1))) void*)g,
      (__attribute__((address_space(3))) void*)l, 16, 0, 0);
}

__device__ __forceinline__ void lvl_of(int s, int& st, int& w, int& h) {
  if (s < 4096)      { st = 0;    w = 64; h = 64; }
  else if (s < 5120) { st = 4096; w = 32; h = 32; }
  else if (s < 5376) { st = 5120; w = 16; h = 16; }
  else               { st = 5376; w = 8;  h = 8;  }
}

// positional encoding for flattened index s, channel c (matches reference sine_pos)
__device__ __forceinline__ float pos_enc(int s, int c) {
  int st, w, h; lvl_of(s, st, w, h);
  int p = s - st, xi = p % w, yi = p / w;
  float v; int f;
  if (c < 128) { v = (yi + 1.0f) / (h + 1e-6f) * 6.28318f; f = c; }
  else         { v = (xi + 1.0f) / (w + 1e-6f) * 6.28318f; f = c - 128; }
  float t = exp2f((float)(f >> 1) * 0.20762050f);
  float arg = v / t;
  return (f & 1) ? cosf(arg) : sinf(arg);
}

// ---------------- dtype detection: ln1_s == ones ----------------
__global__ void detect_kernel(const void* __restrict__ ones_vec, int* __restrict__ flag) {
  unsigned u = *(const unsigned*)ones_vec;
  *flag = (u == 0x3F800000u) ? 0 : 1;
}

// ---------------- zero fill ----------------
__global__ __launch_bounds__(256) void zero_kernel(float* __restrict__ p, int n) {
  int i = blockIdx.x * 256 + threadIdx.x;
  if (i < n) p[i] = 0.f;
}

// ---------------- weight transpose: out[n*K+k] = in[k*N+n] (bf16 out) ----------------
__global__ __launch_bounds__(256) void wtrans_kernel(const int* __restrict__ dflag,
    const void* __restrict__ in, short* __restrict__ out, int K, int N) {
  int bf = *dflag;
  long total = (long)N * K;
  long idx = (long)blockIdx.x * 256 + threadIdx.x;
  if (idx >= total) return;
  long n = idx / K, k = idx - n * K;
  out[idx] = ldbs(in, k * (long)N + n, bf);
}

// ---------------- conv weight transpose: out[lvl][oc][tap*256+c] = in[lvl][oc][c][tap] ----------------
__global__ __launch_bounds__(256) void wconvt_kernel(const int* __restrict__ dflag,
    const void* __restrict__ in, short* __restrict__ out) {
  int bf = *dflag;
  int idx = blockIdx.x * 256 + threadIdx.x;
  if (idx >= 4 * 256 * 2304) return;
  int k = idx % 2304;     // tap*256 + c
  int r = idx / 2304;     // lvl*256 + oc
  int tap = k >> 8, c = k & 255;
  out[idx] = ldbs(in, ((long)r * 256 + c) * 9 + tap, bf);
}

// ---------------- MFMA bf16 GEMM, fp32 accumulate ----------------
__global__ __launch_bounds__(256) void mgemm_kernel(
    const int* __restrict__ dflag,
    const void* __restrict__ A, const void* __restrict__ Bm,
    const void* __restrict__ bias, const void* __restrict__ bias2, void* __restrict__ C,
    int M, int N, int K, int lda, int ldb, int ldc, int Nsplit,
    long sA, long sB, long sC, long oB, long oBias, long oC,
    int flags, int tAc, int tBc, int tCc, int tBT, int ksplit) {
  int bf = *dflag;
  int tA = rt(tAc, bf), tB = rt(tBc, bf), tC = rt(tCc, bf);
  int bz = blockIdx.z, ks = 0;
  if (ksplit > 1) { bz = blockIdx.z / ksplit; ks = blockIdx.z - bz * ksplit; }
  int Kc = K / ksplit;
  int kbeg = ks * Kc, kend = kbeg + Kc;
  long baseA = (long)bz * sA;
  long baseC = (long)bz * sC + oC;
  int m0 = blockIdx.y * 64, n0 = blockIdx.x * 128;
  int tid = threadIdx.x;
  int wave = tid >> 6, lane = tid & 63;
  int wm = wave >> 1, wn = wave & 1;
  int quad = lane >> 4, l16 = lane & 15;

  __shared__ __align__(16) short As[64][40];
  __shared__ __align__(16) short Bs[128][40];

  floatx4 acc[2][4];
  #pragma unroll
  for (int i = 0; i < 2; ++i)
    #pragma unroll
    for (int j = 0; j < 4; ++j) acc[i][j] = floatx4{0.f, 0.f, 0.f, 0.f};

  int am_ = tid >> 2;
  int ak  = (tid & 3) * 8;
  int bk2 = tid >> 4;
  int bnc = tid & 15;
  int bcol = n0 + bnc * 8;
  if (bcol + 8 > N) bcol = N - 8;
  long cbO = (long)bz * sB + oB + bcol;
  int bn_ = tid & 127;
  int bkc = (tid >> 7) * 16;
  int brow = n0 + bn_; if (brow >= N) brow = N - 1;

  auto loadA = [&](int kx, short8& v) {
    long src = baseA + (long)(m0 + am_) * lda + kx + ak;
    if (tA) v = *(const short8*)((const short*)A + src);
    else {
      const float* f = (const float*)A + src;
      floatx4 f0 = *(const floatx4*)f, f1 = *(const floatx4*)(f + 4);
      v[0]=f2bs(f0[0]); v[1]=f2bs(f0[1]); v[2]=f2bs(f0[2]); v[3]=f2bs(f0[3]);
      v[4]=f2bs(f1[0]); v[5]=f2bs(f1[1]); v[6]=f2bs(f1[2]); v[7]=f2bs(f1[3]);
    }
  };
  auto loadBold = [&](int krow, short8& v) {
    if (tB) v = *(const short8*)((const short*)Bm + (long)krow * ldb + cbO);
    else {
      const float* f = (const float*)Bm + (long)krow * ldb + cbO;
      floatx4 f0 = *(const floatx4*)f, f1 = *(const floatx4*)(f + 4);
      v[0]=f2bs(f0[0]); v[1]=f2bs(f0[1]); v[2]=f2bs(f0[2]); v[3]=f2bs(f0[3]);
      v[4]=f2bs(f1[0]); v[5]=f2bs(f1[1]); v[6]=f2bs(f1[2]); v[7]=f2bs(f1[3]);
    }
  };
  auto loadBT = [&](int kx, short8& v0, short8& v1) {
    const short* p = (const short*)Bm + (long)brow * ldb + kx + bkc;
    v0 = *(const short8*)p;
    v1 = *(const short8*)(p + 8);
  };

  short8 vA, vB0, vB1;
  loadA(kbeg, vA);
  if (tBT) loadBT(kbeg, vB0, vB1);
  else { loadBold(kbeg + bk2, vB0); loadBold(kbeg + bk2 + 16, vB1); }

  for (int k0 = kbeg; k0 < kend; k0 += 32) {
    if (k0 != kbeg) __syncthreads();
    *(short8*)&As[am_][ak] = vA;
    if (tBT) {
      *(short8*)&Bs[bn_][bkc]     = vB0;
      *(short8*)&Bs[bn_][bkc + 8] = vB1;
    } else {
      #pragma unroll
      for (int j = 0; j < 8; ++j) {
        Bs[bnc * 8 + j][bk2]      = vB0[j];
        Bs[bnc * 8 + j][bk2 + 16] = vB1[j];
      }
    }
    __syncthreads();
    int kn = k0 + 32;
    if (kn < kend) {
      loadA(kn, vA);
      if (tBT) loadBT(kn, vB0, vB1);
      else { loadBold(kn + bk2, vB0); loadBold(kn + bk2 + 16, vB1); }
    }
    short8 af[2], bfr[4];
    #pragma unroll
    for (int i = 0; i < 2; ++i)
      af[i] = *(const short8*)&As[wm * 32 + i * 16 + l16][quad * 8];
    #pragma unroll
    for (int j = 0; j < 4; ++j)
      bfr[j] = *(const short8*)&Bs[wn * 64 + j * 16 + l16][quad * 8];
    #pragma unroll
    for (int i = 0; i < 2; ++i)
      #pragma unroll
      for (int j = 0; j < 4; ++j)
        acc[i][j] = __builtin_amdgcn_mfma_f32_16x16x32_bf16(af[i], bfr[j], acc[i][j], 0, 0, 0);
  }

  #pragma unroll
  for (int i = 0; i < 2; ++i) {
    int m = m0 + wm * 32 + i * 16 + quad * 4;
    #pragma unroll
    for (int j = 0; j < 4; ++j) {
      int n = n0 + wn * 64 + j * 16 + l16;
      if (n >= N) continue;
      float bn_add = 0.f;
      if ((flags & 1) && ks == 0) {
        bn_add = (bias2 != nullptr && n >= Nsplit) ? ldt(bias2, n - Nsplit, tB)
                                                   : ldt(bias, oBias + n, tB);
      }
      #pragma unroll
      for (int r = 0; r < 4; ++r) {
        float v = acc[i][j][r] + bn_add;
        if ((flags & 2) && ks == 0) v += ldt(bias, oBias + m + r, tB);
        long off = baseC + (long)(m + r) * ldc + n;
        if (ksplit > 1) {
          atomicAdd((float*)C + off, v);
        } else {
          if (flags & 8) v += ldt(C, off, tC);
          if (flags & 4) v = fmaxf(v, 0.f);
          stt(C, off, tC, v);
        }
      }
    }
  }
}

// ---------------- encoder GEMM v2: K=256 resident A-tile, B fragments direct from L2 ----------------
// do_sm=1: softmax over each 16-col group for n >= Nsplit (fused attention-weight softmax).
__global__ __launch_bounds__(256) void egemm_kernel(const int* __restrict__ dflag,
    const void* __restrict__ A, const short* __restrict__ Bt,
    const void* __restrict__ bias, const void* __restrict__ bias2, void* __restrict__ C,
    int N, int ldc, int Nsplit, int tAc, int tCc, int do_sm) {
  int bf = *dflag;
  int tA = rt(tAc, bf), tC = rt(tCc, bf);
  int m0 = blockIdx.y * 64, n0 = blockIdx.x * 128;
  int tid = threadIdx.x;
  int wave = tid >> 6, lane = tid & 63;
  int wm = wave >> 1, wn = wave & 1;
  int quad = lane >> 4, l16 = lane & 15;

  __shared__ __align__(16) short As[64][264];

  floatx4 acc[2][4];
  #pragma unroll
  for (int i = 0; i < 2; ++i)
    #pragma unroll
    for (int j = 0; j < 4; ++j) acc[i][j] = floatx4{0.f, 0.f, 0.f, 0.f};

  // stage full A tile (64 x 256) once
  {
    int r = tid >> 2, c0 = (tid & 3) * 64;
    if (tA) {
      const short* s = (const short*)A + (long)(m0 + r) * 256 + c0;
      #pragma unroll
      for (int c = 0; c < 64; c += 8)
        *(short8*)&As[r][c0 + c] = *(const short8*)(s + c);
    } else {
      const float* f = (const float*)A + (long)(m0 + r) * 256 + c0;
      #pragma unroll
      for (int c = 0; c < 64; c += 8) {
        floatx4 f0 = *(const floatx4*)(f + c);
        floatx4 f1 = *(const floatx4*)(f + c + 4);
        short8 v;
        v[0]=f2bs(f0[0]); v[1]=f2bs(f0[1]); v[2]=f2bs(f0[2]); v[3]=f2bs(f0[3]);
        v[4]=f2bs(f1[0]); v[5]=f2bs(f1[1]); v[6]=f2bs(f1[2]); v[7]=f2bs(f1[3]);
        *(short8*)&As[r][c0 + c] = v;
      }
    }
  }
  __syncthreads();

  // barrier-free K loop; B fragments straight from L2
  #pragma unroll
  for (int k0 = 0; k0 < 256; k0 += 32) {
    short8 af[2], bfr[4];
    #pragma unroll
    for (int j = 0; j < 4; ++j)
      bfr[j] = *(const short8*)(Bt + (long)(n0 + wn * 64 + j * 16 + l16) * 256 + k0 + quad * 8);
    #pragma unroll
    for (int i = 0; i < 2; ++i)
      af[i] = *(const short8*)&As[wm * 32 + i * 16 + l16][k0 + quad * 8];
    #pragma unroll
    for (int i = 0; i < 2; ++i)
      #pragma unroll
      for (int j = 0; j < 4; ++j)
        acc[i][j] = __builtin_amdgcn_mfma_f32_16x16x32_bf16(af[i], bfr[j], acc[i][j], 0, 0, 0);
  }

  #pragma unroll
  for (int i = 0; i < 2; ++i) {
    int m = m0 + wm * 32 + i * 16 + quad * 4;
    #pragma unroll
    for (int j = 0; j < 4; ++j) {
      int n = n0 + wn * 64 + j * 16 + l16;
      if (n >= N) continue;
      float bn_add = (bias2 != nullptr && n >= Nsplit) ? ldt(bias2, n - Nsplit, bf)
                                                       : ldt(bias, n, bf);
      float vv[4];
      #pragma unroll
      for (int r = 0; r < 4; ++r) vv[r] = acc[i][j][r] + bn_add;
      if (do_sm && n0 + wn * 64 + j * 16 >= Nsplit) {
        #pragma unroll
        for (int r = 0; r < 4; ++r) {
          float x = vv[r];
          float mx = x;
          #pragma unroll
          for (int msk = 1; msk < 16; msk <<= 1)
            mx = fmaxf(mx, __shfl_xor(mx, msk));
          float e = expf(x - mx);
          float ssum = e;
          #pragma unroll
          for (int msk = 1; msk < 16; msk <<= 1)
            ssum += __shfl_xor(ssum, msk);
          vv[r] = e / ssum;
        }
      }
      #pragma unroll
      for (int r = 0; r < 4; ++r)
        stt(C, (long)(m + r) * ldc + n, tC, vv[r]);
    }
  }
}

// ---------------- fused FFN v6: weights via async global_load_lds, triple-buffered ----------------
// out = relu(src@W1 + b1) @ W2 + b2. W1t [2048][256], W2t [256][2048].
__global__ __launch_bounds__(256) void ffn_kernel(const int* __restrict__ dflag,
    const float* __restrict__ src, const short* __restrict__ W1t, const void* __restrict__ b1,
    const short* __restrict__ W2t, const void* __restrict__ b2, bf16* __restrict__ out) {
  int bf = *dflag;
  long m0 = (long)blockIdx.x * 32;
  int tid = threadIdx.x;
  int wn = tid >> 6, lane = tid & 63;
  int quad = lane >> 4, l16 = lane & 15;

  __shared__ __align__(16) short As[32][264];   // src tile, K=256 resident
  __shared__ __align__(16) short Hs[32][136];   // hidden chunk (128 k)
  __shared__ __align__(16) short Bs3[3][4096];  // weight tile buffers [128][32]

  // per-lane staging map: n = slot*16 + lane/4, k = (lane&3)*8, slot = wn*2 + t
  int sn = lane >> 2, sk = (lane & 3) * 8;

  floatx4 acc2[2][4];
  #pragma unroll
  for (int i = 0; i < 2; ++i)
    #pragma unroll
    for (int j = 0; j < 4; ++j) acc2[i][j] = floatx4{0.f, 0.f, 0.f, 0.f};

  // stage src tile once (32 x 256)
  {
    int r = tid >> 3, c0 = (tid & 7) * 32;
    const float* sp = src + (m0 + r) * 256 + c0;
    #pragma unroll
    for (int c = 0; c < 32; c += 8) {
      floatx4 f0 = *(const floatx4*)(sp + c);
      floatx4 f1 = *(const floatx4*)(sp + c + 4);
      short8 v;
      v[0]=f2bs(f0[0]); v[1]=f2bs(f0[1]); v[2]=f2bs(f0[2]); v[3]=f2bs(f0[3]);
      v[4]=f2bs(f1[0]); v[5]=f2bs(f1[1]); v[6]=f2bs(f1[2]); v[7]=f2bs(f1[3]);
      *(short8*)&As[r][c0 + c] = v;
    }
  }

  auto stageW1 = [&](int buf, int ch, int k1) {
    #pragma unroll
    for (int t = 0; t < 2; ++t) {
      int slot = wn * 2 + t;
      int n = slot * 16 + sn;
      const short* gp = W1t + (long)(ch * 128 + n) * 256 + k1 + sk;
      gload_lds16(gp, &Bs3[buf][slot * 512]);
    }
  };
  auto stageW2 = [&](int buf, int ch, int t2) {
    int nh = t2 >> 2, k2 = (t2 & 3) * 32;
    #pragma unroll
    for (int t = 0; t < 2; ++t) {
      int slot = wn * 2 + t;
      int n = slot * 16 + sn;
      const short* gp = W2t + (long)(nh * 128 + n) * 2048 + ch * 128 + k2 + sk;
      gload_lds16(gp, &Bs3[buf][slot * 512]);
    }
  };

  __syncthreads();   // As visible

  for (int ch = 0; ch < 16; ++ch) {
    floatx4 acc1[2][2];
    #pragma unroll
    for (int i = 0; i < 2; ++i)
      #pragma unroll
      for (int j = 0; j < 2; ++j) acc1[i][j] = floatx4{0.f, 0.f, 0.f, 0.f};

    // ---- stage1: H = relu(src @ W1chunk) ----
    stageW1(0, ch, 0);
    #pragma unroll
    for (int s = 0; s < 8; ++s) {
      if (s < 7) stageW1((s + 1) % 3, ch, (s + 1) * 32);
      __syncthreads();   // drains loads; buf[s%3] ready
      const short* bb = &Bs3[s % 3][0];
      short8 af[2], bfr[2];
      #pragma unroll
      for (int j = 0; j < 2; ++j)
        bfr[j] = *(const short8*)(bb + (wn * 32 + j * 16 + l16) * 32 + quad * 8);
      #pragma unroll
      for (int i = 0; i < 2; ++i)
        af[i] = *(const short8*)&As[i * 16 + l16][s * 32 + quad * 8];
      #pragma unroll
      for (int i = 0; i < 2; ++i)
        #pragma unroll
        for (int j = 0; j < 2; ++j)
          acc1[i][j] = __builtin_amdgcn_mfma_f32_16x16x32_bf16(af[i], bfr[j], acc1[i][j], 0, 0, 0);
    }

    __syncthreads();   // all stage1 reads done (also guards Hs overwrite)
    #pragma unroll
    for (int i = 0; i < 2; ++i)
      #pragma unroll
      for (int j = 0; j < 2; ++j) {
        int nl = wn * 32 + j * 16 + l16;
        float bb = ldt(b1, (long)ch * 128 + nl, bf);
        #pragma unroll
        for (int r = 0; r < 4; ++r) {
          float hv = fmaxf(acc1[i][j][r] + bb, 0.f);
          Hs[i * 16 + quad * 4 + r][nl] = f2bs(hv);
        }
      }
    stageW2(0, ch, 0);   // prefetch first stage2 tile (buf0 reads finished at s=6<7)
    __syncthreads();     // Hs visible + stage2 buf0 ready

    // ---- stage2: acc2 += H @ W2chunk ----
    #pragma unroll
    for (int s = 0; s < 8; ++s) {
      if (s < 7) stageW2((s + 1) % 3, ch, s + 1);
      if (s) __syncthreads();
      int nh = s >> 2;
      const short* bb = &Bs3[s % 3][0];
      short8 ah[2], bfr[2];
      #pragma unroll
      for (int j = 0; j < 2; ++j)
        bfr[j] = *(const short8*)(bb + (wn * 32 + j * 16 + l16) * 32 + quad * 8);
      int k2 = (s & 3) * 32;
      #pragma unroll
      for (int i = 0; i < 2; ++i)
        ah[i] = *(const short8*)&Hs[i * 16 + l16][k2 + quad * 8];
      #pragma unroll
      for (int i = 0; i < 2; ++i)
        #pragma unroll
        for (int j = 0; j < 2; ++j)
          acc2[i][nh * 2 + j] =
              __builtin_amdgcn_mfma_f32_16x16x32_bf16(ah[i], bfr[j], acc2[i][nh * 2 + j], 0, 0, 0);
    }
    __syncthreads();   // all stage2 reads done before next chunk's staging
  }

  #pragma unroll
  for (int i = 0; i < 2; ++i) {
    long m = m0 + i * 16 + quad * 4;
    #pragma unroll
    for (int nh = 0; nh < 2; ++nh)
      #pragma unroll
      for (int j = 0; j < 2; ++j) {
        int n = nh * 128 + wn * 32 + j * 16 + l16;
        float bb = ldt(b2, n, bf);
        #pragma unroll
        for (int r = 0; r < 4; ++r)
          out[(m + r) * 256 + n] = __float2bfloat16(acc2[i][nh * 2 + j][r] + bb);
      }
  }
}

// ---------------- 3x3 conv as MFMA implicit GEMM (pre-transposed bf16 weights) ----------------
__global__ __launch_bounds__(256) void mconv_kernel(const short* __restrict__ Wc,
    const float* __restrict__ X, float* __restrict__ Y, int H, int Wd, int lw) {
  int bz = blockIdx.z;
  int HW = H * Wd;
  const float* Xb = X + (long)bz * 256 * HW;
  float* Yb = Y + (long)bz * 256 * HW;
  int m0 = blockIdx.y * 64, n0 = blockIdx.x * 128;
  int tid = threadIdx.x;
  int wave = tid >> 6, lane = tid & 63;
  int wm = wave >> 1, wn = wave & 1;
  int quad = lane >> 4, l16 = lane & 15;

  __shared__ __align__(16) short As[64][40];
  __shared__ __align__(16) short Bs[128][40];

  floatx4 acc[2][4];
  #pragma unroll
  for (int i = 0; i < 2; ++i)
    #pragma unroll
    for (int j = 0; j < 4; ++j) acc[i][j] = floatx4{0.f, 0.f, 0.f, 0.f};

  int am_ = tid >> 2;
  int ak  = (tid & 3) * 8;
  int bn_ = tid & 127;
  int bkc = (tid >> 7) * 16;
  int gn  = n0 + bn_; if (gn >= HW) gn = HW - 1;
  int y = gn >> lw, x = gn & (Wd - 1);

  const short* Arow = Wc + (long)(m0 + am_) * 2304 + ak;

  short8 vA;
  float rB[16];
  auto pre = [&](int k0) {
    vA = *(const short8*)(Arow + k0);
    int tap = k0 >> 8;
    int dy = tap / 3 - 1, dx = tap % 3 - 1;
    bool ok = ((unsigned)(y + dy) < (unsigned)H) && ((unsigned)(x + dx) < (unsigned)Wd);
    const float* xp = Xb + (long)((k0 & 255) + bkc) * HW + gn + dy * Wd + dx;
    #pragma unroll
    for (int j = 0; j < 16; ++j)
      rB[j] = ok ? xp[(long)j * HW] : 0.f;
  };

  pre(0);
  for (int k0 = 0; k0 < 2304; k0 += 32) {
    if (k0) __syncthreads();
    *(short8*)&As[am_][ak] = vA;
    #pragma unroll
    for (int j = 0; j < 16; ++j) Bs[bn_][bkc + j] = f2bs(rB[j]);
    __syncthreads();
    if (k0 + 32 < 2304) pre(k0 + 32);
    short8 af[2], bfr[4];
    #pragma unroll
    for (int i = 0; i < 2; ++i)
      af[i] = *(const short8*)&As[wm * 32 + i * 16 + l16][quad * 8];
    #pragma unroll
    for (int j = 0; j < 4; ++j)
      bfr[j] = *(const short8*)&Bs[wn * 64 + j * 16 + l16][quad * 8];
    #pragma unroll
    for (int i = 0; i < 2; ++i)
      #pragma unroll
      for (int j = 0; j < 4; ++j)
        acc[i][j] = __builtin_amdgcn_mfma_f32_16x16x32_bf16(af[i], bfr[j], acc[i][j], 0, 0, 0);
  }

  #pragma unroll
  for (int i = 0; i < 2; ++i) {
    int m = m0 + wm * 32 + i * 16 + quad * 4;
    #pragma unroll
    for (int j = 0; j < 4; ++j) {
      int n = n0 + wn * 64 + j * 16 + l16;
      if (n >= HW) continue;
      #pragma unroll
      for (int r = 0; r < 4; ++r)
        Yb[(long)(m + r) * HW + n] = acc[i][j][r];
    }
  }
}

// ---------------- GroupNorm in-place (fp32 X) ----------------
__global__ __launch_bounds__(256) void gn_kernel(const int* __restrict__ dflag,
    float* __restrict__ X, const void* __restrict__ gs, const void* __restrict__ gb,
    long po, int HW, int relu) {
  int bf = *dflag;
  int g = blockIdx.x, b = blockIdx.y;
  float* base = X + ((long)b * 256 + g * 8) * HW;
  int n = 8 * HW;
  int t = threadIdx.x;
  float s1 = 0.f, s2 = 0.f;
  for (int i = t; i < n; i += 256) { float v = base[i]; s1 += v; s2 += v * v; }
  __shared__ float r1[256], r2[256];
  r1[t] = s1; r2[t] = s2; __syncthreads();
  for (int sh = 128; sh > 0; sh >>= 1) {
    if (t < sh) { r1[t] += r1[t + sh]; r2[t] += r2[t + sh]; }
    __syncthreads();
  }
  float mu = r1[0] / n;
  float var = fmaxf(r2[0] / n - mu * mu, 0.f);
  float inv = rsqrtf(var + 1e-5f);
  for (int i = t; i < n; i += 256) {
    int c = g * 8 + i / HW;
    float v = (base[i] - mu) * inv * ldt(gs, po + c, bf) + ldt(gb, po + c, bf);
    if (relu) v = fmaxf(v, 0.f);
    base[i] = v;
  }
}

// ---------------- bilinear 0.5x downsample (2x2 avg) added into target ----------------
__global__ __launch_bounds__(256) void dsadd_kernel(float* __restrict__ T,
    const float* __restrict__ P, int H, int Wd) {
  int idx = blockIdx.x * 256 + threadIdx.x;
  int total = BB * 256 * H * Wd;
  if (idx >= total) return;
  int x = idx % Wd, y = (idx / Wd) % H;
  int bc = idx / (Wd * H);
  const float* Pp = P + (((long)bc * (2 * H) + 2 * y) * (2 * Wd) + 2 * x);
  T[idx] += 0.25f * (Pp[0] + Pp[1] + Pp[2 * Wd] + Pp[2 * Wd + 1]);
}

// ---------------- build src (fp32) from FPN maps ----------------
__global__ __launch_bounds__(256) void srcbuild_kernel(const float* __restrict__ O0,
    const float* __restrict__ O1, const float* __restrict__ O2, const float* __restrict__ O3,
    float* __restrict__ src) {
  int idx = blockIdx.x * 256 + threadIdx.x;
  if (idx >= MTOT * 256) return;
  int c = idx & 255;
  int bs = idx >> 8;
  int s = bs % S_TOT, b = bs / S_TOT;
  int st, w, h; lvl_of(s, st, w, h);
  const float* O = (s < 4096) ? O0 : (s < 5120) ? O1 : (s < 5376) ? O2 : O3;
  int HW = w * h;
  src[idx] = O[((long)(b * 256 + c)) * HW + (s - st)];
}

// ---------------- layer-0 q = bf16(src + pos) ----------------
__global__ __launch_bounds__(256) void qinit_kernel(const float* __restrict__ src,
    bf16* __restrict__ q) {
  int idx = blockIdx.x * 256 + threadIdx.x;
  if (idx >= MTOT * 256) return;
  int c = idx & 255;
  int bs = idx >> 8;
  int s = bs % S_TOT;
  q[idx] = __float2bfloat16(src[idx] + pos_enc(s, c));
}

// ---------------- multi-scale deformable sampling, 4 d-channels per thread ----------------
__global__ __launch_bounds__(256) void deform_kernel(const bf16* __restrict__ value,
    const bf16* __restrict__ oaw, bf16* __restrict__ attn) {
  int idx = blockIdx.x * 256 + threadIdx.x;
  if (idx >= MTOT * 64) return;
  int d4 = idx & 7;          // which quad of d (d = d4*4 .. d4*4+3)
  int h = (idx >> 3) & 7;
  int bs = idx >> 6;
  int s = bs % S_TOT, b = bs / S_TOT;
  int stS, wS, hS; lvl_of(s, stS, wS, hS);
  int pl = s - stS;
  float rx = ((pl % wS) + 0.5f) / wS;
  float ry = ((pl / wS) + 0.5f) / hS;
  const bf16* offr = oaw + (long)bs * 384 + h * 32;
  const bf16* awr  = oaw + (long)bs * 384 + 256 + h * 16;
  const short* vbase = (const short*)value + (long)b * S_TOT * 256 + h * 32 + d4 * 4;
  const int LW[4] = {64, 32, 16, 8}, LST[4] = {0, 4096, 5120, 5376};
  float acc0 = 0.f, acc1 = 0.f, acc2 = 0.f, acc3 = 0.f;
  #pragma unroll
  for (int l = 0; l < 4; ++l) {
    int w = LW[l], hh = LW[l], st = LST[l];
    #pragma unroll
    for (int p = 0; p < 4; ++p) {
      float ox = __bfloat162float(offr[l * 8 + p * 2 + 0]);
      float oy = __bfloat162float(offr[l * 8 + p * 2 + 1]);
      float x = rx * w + ox - 0.5f;
      float y = ry * hh + oy - 0.5f;
      float x0f = floorf(x), y0f = floorf(y);
      int x0 = (int)x0f, y0 = (int)y0f;
      float fx = x - x0f, fy = y - y0f;
      float a = __bfloat162float(awr[l * 4 + p]);
      float s0 = 0.f, s1 = 0.f, s2 = 0.f, s3 = 0.f;
      #pragma unroll
      for (int ty2 = 0; ty2 < 2; ++ty2) {
        int yi = y0 + ty2;
        float wy = ty2 ? fy : 1.f - fy;
        bool vy = (yi >= 0) && (yi < hh);
        int yc = min(max(yi, 0), hh - 1);
        #pragma unroll
        for (int tx2 = 0; tx2 < 2; ++tx2) {
          int xi = x0 + tx2;
          float wx = tx2 ? fx : 1.f - fx;
          bool vx = (xi >= 0) && (xi < w);
          int xc = min(max(xi, 0), w - 1);
          short4v v = *(const short4v*)(vbase + (long)(st + yc * w + xc) * 256);
          float wxy = (vx && vy) ? wy * wx : 0.f;
          s0 += wxy * bs2f(v[0]);
          s1 += wxy * bs2f(v[1]);
          s2 += wxy * bs2f(v[2]);
          s3 += wxy * bs2f(v[3]);
        }
      }
      acc0 += a * s0; acc1 += a * s1; acc2 += a * s2; acc3 += a * s3;
    }
  }
  short4v o;
  o[0] = f2bs(acc0); o[1] = f2bs(acc1); o[2] = f2bs(acc2); o[3] = f2bs(acc3);
  *(short4v*)((short*)attn + (long)bs * 256 + h * 32 + d4 * 4) = o;
}

// ---------------- LayerNorm(src + resid_bf16), wave-per-row, optional q = bf16(out + pos) ----------------
__global__ __launch_bounds__(256) void ln_kernel(const int* __restrict__ dflag,
    float* __restrict__ src, const bf16* __restrict__ resid,
    const void* __restrict__ g, const void* __restrict__ b, bf16* __restrict__ qout) {
  int bf = *dflag;
  long r = (long)blockIdx.x * 4 + (threadIdx.x >> 6);
  int lane = threadIdx.x & 63;
  float* x = src + r * 256;
  const bf16* a = resid + r * 256;
  float v[4];
  float s1 = 0.f, s2 = 0.f;
  #pragma unroll
  for (int k = 0; k < 4; ++k) {
    int c = lane + 64 * k;
    float t = x[c] + __bfloat162float(a[c]);
    v[k] = t; s1 += t; s2 += t * t;
  }
  #pragma unroll
  for (int msk = 1; msk < 64; msk <<= 1) {
    s1 += __shfl_xor(s1, msk);
    s2 += __shfl_xor(s2, msk);
  }
  float mu = s1 * (1.f / 256.f);
  float var = fmaxf(s2 * (1.f / 256.f) - mu * mu, 0.f);
  float inv = rsqrtf(var + 1e-5f);
  int s = (int)(r % S_TOT);
  #pragma unroll
  for (int k = 0; k < 4; ++k) {
    int c = lane + 64 * k;
    float o = (v[k] - mu) * inv * ldt(g, c, bf) + ldt(b, c, bf);
    x[c] = o;
    if (qout) qout[r * 256 + c] = __float2bfloat16(o + pos_enc(s, c));
  }
}

// ---------------- unflatten src -> out chunks 1..4 ----------------
__global__ __launch_bounds__(256) void unflat_kernel(const int* __restrict__ dflag,
    const float* __restrict__ src, void* __restrict__ out) {
  int bf = *dflag;
  int idx = blockIdx.x * 256 + threadIdx.x;
  if (idx >= MTOT * 256) return;
  int c = idx & 255;
  int bs = idx >> 8;
  int s = bs % S_TOT, b = bs / S_TOT;
  int st, w, h; lvl_of(s, st, w, h);
  int HW = w * h;
  long base = (s < 4096) ? 2097152L : (s < 5120) ? 4194304L : (s < 5376) ? 4718592L : 4849664L;
  stt(out, base + ((long)(b * 256 + c)) * HW + (s - st), bf, src[idx]);
}

// ---------------- sentinel ----------------
__global__ __launch_bounds__(256) void sentinel_kernel(float* __restrict__ out, int n) {
  int i = blockIdx.x * 256 + threadIdx.x;
  if (i < n) out[i] = 999.0f;
}

// =====================================================================
extern "C" void kernel_launch(void* const* d_in, const int* in_sizes, int n_in,
                              void* d_out, int out_size, void* d_ws, size_t ws_size,
                              hipStream_t stream) {
  (void)in_sizes; (void)n_in;
  // 7,659,520 activations + 64 flag + 638,976 transposed-weight floats
  const size_t NEED = (7659520ull + 64ull + 638976ull) * 4ull;
  if (ws_size < NEED) {
    int nf = out_size / 2;
    sentinel_kernel<<<(nf + 255) / 256, 256, 0, stream>>>((float*)d_out, nf);
    return;
  }

  const void* feat[4] = {d_in[0], d_in[1], d_in[2], d_in[3]};
  const void* latw[4] = {d_in[4], d_in[5], d_in[6], d_in[7]};
  const void *latgns = d_in[8], *latgnb = d_in[9];
  const void* outw = d_in[10];
  const void *outgns = d_in[11], *outgnb = d_in[12];
  const void *offw = d_in[13], *offb_ = d_in[14], *aww = d_in[15], *awb_ = d_in[16];
  const void *valw = d_in[17], *valb_ = d_in[18], *projw = d_in[19], *projb_ = d_in[20];
  const void *f1w = d_in[21], *f1b = d_in[22], *f2w = d_in[23], *f2b = d_in[24];
  const void *ln1s = d_in[25], *ln1b = d_in[26], *ln2s = d_in[27], *ln2b = d_in[28];
  const void *maskw = d_in[29], *maskb = d_in[30];

  float* W = (float*)d_ws;
  float* srcb  = W;
  float* fpn_a = W;
  bf16*  oawbf = (bf16*)(W + 2785280);
  bf16*  tmpbf = oawbf;
  bf16*  qbf   = (bf16*)(W + 4874240);
  bf16*  valbf = (bf16*)(W + 6266880);
  float* ObF   = W + 4874240;
  float* Ob[4] = {ObF, ObF + 2097152, ObF + 2621440, ObF + 2752512};
  int*   dflag = (int*)(W + 7659520);
  short* wtS   = (short*)(W + 7659584);
  short* valt  = wtS;             // [256][256]
  short* projt = wtS + 65536;     // [256][256]
  short* oawt  = wtS + 131072;    // [384][256]
  short* w1t   = wtS + 229376;    // [2048][256]
  short* w2t   = wtS + 753664;    // [256][2048]
  // conv weights (bf16, [4][256][2304]) live in the encoder-phase oawbf region;
  // FPN finishes before the encoder overwrites it.
  short* wconvt = (short*)(W + 2785280);   // 2,359,296 shorts, ends at W+3964928

  detect_kernel<<<1, 1, 0, stream>>>(ln1s, dflag);
  // pre-transpose encoder weights to bf16 [N][K]
  wtrans_kernel<<<(65536 + 255) / 256, 256, 0, stream>>>(dflag, valw, valt, 256, 256);
  wtrans_kernel<<<(65536 + 255) / 256, 256, 0, stream>>>(dflag, projw, projt, 256, 256);
  wtrans_kernel<<<(65536 + 255) / 256, 256, 0, stream>>>(dflag, offw, oawt, 256, 256);
  wtrans_kernel<<<(32768 + 255) / 256, 256, 0, stream>>>(dflag, aww, oawt + 65536, 256, 128);
  wtrans_kernel<<<(524288 + 255) / 256, 256, 0, stream>>>(dflag, f1w, w1t, 256, 2048);
  wtrans_kernel<<<(524288 + 255) / 256, 256, 0, stream>>>(dflag, f2w, w2t, 2048, 256);
  wconvt_kernel<<<(2359296 + 255) / 256, 256, 0, stream>>>(dflag, outw, wconvt);

  const int M = MTOT;
  auto mgemm = [&](const void* A, const void* B, const void* bias, const void* bias2,
                   void* C, int Mi, int Ni, int Ki, int lda, int ldb, int ldc, int Nsplit,
                   long sA, long sB, long sC, long oB, long oBias, long oC,
                   int batch, int flags, int tA, int tB, int tC, int tBT, int ksplit) {
    dim3 g((Ni + 127) / 128, Mi / 64, batch * ksplit);
    mgemm_kernel<<<g, 256, 0, stream>>>(dflag, A, B, bias, bias2, C, Mi, Ni, Ki,
                                        lda, ldb, ldc, Nsplit,
                                        sA, sB, sC, oB, oBias, oC, flags, tA, tB, tC, tBT,
                                        ksplit);
  };
  auto egemm = [&](const void* A, const short* Bt, const void* bias, const void* bias2,
                   void* C, int Ni, int ldc, int Nsplit, int tA, int tC, int do_sm) {
    dim3 g((Ni + 127) / 128, M / 64, 1);
    egemm_kernel<<<g, 256, 0, stream>>>(dflag, A, Bt, bias, bias2, C, Ni, ldc, Nsplit,
                                        tA, tC, do_sm);
  };

  // ---------------- FPN ----------------
  const int LVL[4] = {64, 32, 16, 8};
  const int LGW[4] = {6, 5, 4, 3};
  const int CIN[4] = {256, 512, 1024, 2048};
  const int KSP[4] = {1, 4, 8, 16};   // split-K for under-parallelized laterals
  for (int i = 0; i < 4; ++i) {
    int H = LVL[i], HW = H * H, Cin = CIN[i];
    int ksp = KSP[i];
    if (ksp > 1)
      zero_kernel<<<(BB * 256 * HW + 255) / 256, 256, 0, stream>>>(fpn_a, BB * 256 * HW);
    mgemm(latw[i], feat[i], nullptr, nullptr, fpn_a, 256, HW, Cin,
          Cin, HW, HW, 0, 0, (long)Cin * HW, (long)256 * HW, 0, 0, 0, BB, 0, 2, 2, 0, 0, ksp);
    gn_kernel<<<dim3(32, BB), 256, 0, stream>>>(dflag, fpn_a, latgns, latgnb,
                                                (long)i * 256, HW, 0);
    if (i > 0) {
      int total = BB * 256 * HW;
      dsadd_kernel<<<(total + 255) / 256, 256, 0, stream>>>(fpn_a, Ob[i - 1], H, H);
    }
    {
      dim3 g((HW + 127) / 128, 4, BB);
      mconv_kernel<<<g, 256, 0, stream>>>(wconvt + (long)i * 589824, fpn_a, Ob[i],
                                          H, H, LGW[i]);
    }
    gn_kernel<<<dim3(32, BB), 256, 0, stream>>>(dflag, Ob[i], outgns, outgnb,
                                                (long)i * 256, HW, 1);
  }

  srcbuild_kernel<<<(M * 256) / 256, 256, 0, stream>>>(Ob[0], Ob[1], Ob[2], Ob[3], srcb);
  // layer-0 q (runs after srcbuild fully consumed Ob; qbf aliases Ob[0] safely now)
  qinit_kernel<<<(M * 256) / 256, 256, 0, stream>>>(srcb, qbf);

  // ---------------- encoder layers (shared weights) ----------------
  for (int L = 0; L < 6; ++L) {
    egemm(srcb, valt, valb_, nullptr, valbf, 256, 256, 256, 0, 1, 0);
    egemm(qbf, oawt, offb_, awb_, oawbf, 384, 384, 256, 1, 1, 1);   // fused aw softmax
    deform_kernel<<<(M * 64) / 256, 256, 0, stream>>>(valbf, oawbf, qbf);
    egemm(qbf, projt, projb_, nullptr, tmpbf, 256, 256, 256, 1, 1, 0);
    ln_kernel<<<M / 4, 256, 0, stream>>>(dflag, srcb, tmpbf, ln1s, ln1b, nullptr);
    ffn_kernel<<<M / 32, 256, 0, stream>>>(dflag, srcb, w1t, f1b, w2t, f2b, tmpbf);
    ln_kernel<<<M / 4, 256, 0, stream>>>(dflag, srcb, tmpbf, ln2s, ln2b,
                                         (L < 5) ? qbf : nullptr);
  }

  // ---------------- outputs ----------------
  unflat_kernel<<<(M * 256) / 256, 256, 0, stream>>>(dflag, srcb, d_out);
  mgemm(maskw, d_out, maskb, nullptr, d_out, 256, 4096, 256,
        256, 4096, 4096, 0, 0, 1048576L, 1048576L, 2097152L, 0, 0, BB, 2, 2, 2, 2, 0, 1);
}

// Round 16
// 1822.090 us; speedup vs baseline: 1.3364x; 1.0025x over previous
//
#include <hip/hip_runtime.h>
#include <hip/hip_bf16.h>

typedef __hip_bfloat16 bf16;
typedef __attribute__((ext_vector_type(8))) short short8;
typedef __attribute__((ext_vector_type(4))) short short4v;
typedef __attribute__((ext_vector_type(4))) float floatx4;

#define S_TOT 5440
#define BB 2
#define MTOT (BB * S_TOT)  // 10880

__device__ __forceinline__ float ldt(const void* p, long i, int t) {
  return t ? __bfloat162float(((const bf16*)p)[i]) : ((const float*)p)[i];
}
__device__ __forceinline__ void stt(void* p, long i, int t, float v) {
  if (t) ((bf16*)p)[i] = __float2bfloat16(v);
  else   ((float*)p)[i] = v;
}
__device__ __forceinline__ int rt(int code, int bf) { return code == 2 ? bf : code; }
__device__ __forceinline__ short f2bs(float f) {
  bf16 h = __float2bfloat16(f);
  return *(short*)&h;
}
__device__ __forceinline__ float bs2f(short s) {
  bf16 h = *(bf16*)&s;
  return __bfloat162float(h);
}
__device__ __forceinline__ short ldbs(const void* p, long i, int t) {
  return t ? ((const short*)p)[i] : f2bs(((const float*)p)[i]);
}

// async global->LDS 16B per lane (dest = ldsbase + lane*16)
__device__ __forceinline__ void gload_lds16(const short* g, short* l) {
  __builtin_amdgcn_global_load_lds(
      (const __attribute__((address_space(1))) void*)g,
      (__attribute__((address_space(3))) void*)l, 16, 0, 0);
}

__device__ __forceinline__ void lvl_of(int s, int& st, int& w, int& h) {
  if (s < 4096)      { st = 0;    w = 64; h = 64; }
  else if (s < 5120) { st = 4096; w = 32; h = 32; }
  else if (s < 5376) { st = 5120; w = 16; h = 16; }
  else               { st = 5376; w = 8;  h = 8;  }
}

// positional encoding for flattened index s, channel c (matches reference sine_pos)
__device__ __forceinline__ float pos_enc(int s, int c) {
  int st, w, h; lvl_of(s, st, w, h);
  int p = s - st, xi = p % w, yi = p / w;
  float v; int f;
  if (c < 128) { v = (yi + 1.0f) / (h + 1e-6f) * 6.28318f; f = c; }
  else         { v = (xi + 1.0f) / (w + 1e-6f) * 6.28318f; f = c - 128; }
  float t = exp2f((float)(f >> 1) * 0.20762050f);
  float arg = v / t;
  return (f & 1) ? cosf(arg) : sinf(arg);
}

// ---------------- dtype detection: ln1_s == ones ----------------
__global__ void detect_kernel(const void* __restrict__ ones_vec, int* __restrict__ flag) {
  unsigned u = *(const unsigned*)ones_vec;
  *flag = (u == 0x3F800000u) ? 0 : 1;
}

// ---------------- zero fill ----------------
__global__ __launch_bounds__(256) void zero_kernel(float* __restrict__ p, int n) {
  int i = blockIdx.x * 256 + threadIdx.x;
  if (i < n) p[i] = 0.f;
}

// ---------------- weight transpose: out[n*K+k] = in[k*N+n] (bf16 out) ----------------
__global__ __launch_bounds__(256) void wtrans_kernel(const int* __restrict__ dflag,
    const void* __restrict__ in, short* __restrict__ out, int K, int N) {
  int bf = *dflag;
  long total = (long)N * K;
  long idx = (long)blockIdx.x * 256 + threadIdx.x;
  if (idx >= total) return;
  long n = idx / K, k = idx - n * K;
  out[idx] = ldbs(in, k * (long)N + n, bf);
}

// ---------------- conv weight transpose: out[lvl][oc][tap*256+c] = in[lvl][oc][c][tap] ----------------
__global__ __launch_bounds__(256) void wconvt_kernel(const int* __restrict__ dflag,
    const void* __restrict__ in, short* __restrict__ out) {
  int bf = *dflag;
  int idx = blockIdx.x * 256 + threadIdx.x;
  if (idx >= 4 * 256 * 2304) return;
  int k = idx % 2304;     // tap*256 + c
  int r = idx / 2304;     // lvl*256 + oc
  int tap = k >> 8, c = k & 255;
  out[idx] = ldbs(in, ((long)r * 256 + c) * 9 + tap, bf);
}

// ---------------- MFMA bf16 GEMM, fp32 accumulate ----------------
__global__ __launch_bounds__(256) void mgemm_kernel(
    const int* __restrict__ dflag,
    const void* __restrict__ A, const void* __restrict__ Bm,
    const void* __restrict__ bias, const void* __restrict__ bias2, void* __restrict__ C,
    int M, int N, int K, int lda, int ldb, int ldc, int Nsplit,
    long sA, long sB, long sC, long oB, long oBias, long oC,
    int flags, int tAc, int tBc, int tCc, int tBT, int ksplit) {
  int bf = *dflag;
  int tA = rt(tAc, bf), tB = rt(tBc, bf), tC = rt(tCc, bf);
  int bz = blockIdx.z, ks = 0;
  if (ksplit > 1) { bz = blockIdx.z / ksplit; ks = blockIdx.z - bz * ksplit; }
  int Kc = K / ksplit;
  int kbeg = ks * Kc, kend = kbeg + Kc;
  long baseA = (long)bz * sA;
  long baseC = (long)bz * sC + oC;
  int m0 = blockIdx.y * 64, n0 = blockIdx.x * 128;
  int tid = threadIdx.x;
  int wave = tid >> 6, lane = tid & 63;
  int wm = wave >> 1, wn = wave & 1;
  int quad = lane >> 4, l16 = lane & 15;

  __shared__ __align__(16) short As[64][40];
  __shared__ __align__(16) short Bs[128][40];

  floatx4 acc[2][4];
  #pragma unroll
  for (int i = 0; i < 2; ++i)
    #pragma unroll
    for (int j = 0; j < 4; ++j) acc[i][j] = floatx4{0.f, 0.f, 0.f, 0.f};

  int am_ = tid >> 2;
  int ak  = (tid & 3) * 8;
  int bk2 = tid >> 4;
  int bnc = tid & 15;
  int bcol = n0 + bnc * 8;
  if (bcol + 8 > N) bcol = N - 8;
  long cbO = (long)bz * sB + oB + bcol;
  int bn_ = tid & 127;
  int bkc = (tid >> 7) * 16;
  int brow = n0 + bn_; if (brow >= N) brow = N - 1;

  auto loadA = [&](int kx, short8& v) {
    long src = baseA + (long)(m0 + am_) * lda + kx + ak;
    if (tA) v = *(const short8*)((const short*)A + src);
    else {
      const float* f = (const float*)A + src;
      floatx4 f0 = *(const floatx4*)f, f1 = *(const floatx4*)(f + 4);
      v[0]=f2bs(f0[0]); v[1]=f2bs(f0[1]); v[2]=f2bs(f0[2]); v[3]=f2bs(f0[3]);
      v[4]=f2bs(f1[0]); v[5]=f2bs(f1[1]); v[6]=f2bs(f1[2]); v[7]=f2bs(f1[3]);
    }
  };
  auto loadBold = [&](int krow, short8& v) {
    if (tB) v = *(const short8*)((const short*)Bm + (long)krow * ldb + cbO);
    else {
      const float* f = (const float*)Bm + (long)krow * ldb + cbO;
      floatx4 f0 = *(const floatx4*)f, f1 = *(const floatx4*)(f + 4);
      v[0]=f2bs(f0[0]); v[1]=f2bs(f0[1]); v[2]=f2bs(f0[2]); v[3]=f2bs(f0[3]);
      v[4]=f2bs(f1[0]); v[5]=f2bs(f1[1]); v[6]=f2bs(f1[2]); v[7]=f2bs(f1[3]);
    }
  };
  auto loadBT = [&](int kx, short8& v0, short8& v1) {
    const short* p = (const short*)Bm + (long)brow * ldb + kx + bkc;
    v0 = *(const short8*)p;
    v1 = *(const short8*)(p + 8);
  };

  short8 vA, vB0, vB1;
  loadA(kbeg, vA);
  if (tBT) loadBT(kbeg, vB0, vB1);
  else { loadBold(kbeg + bk2, vB0); loadBold(kbeg + bk2 + 16, vB1); }

  for (int k0 = kbeg; k0 < kend; k0 += 32) {
    if (k0 != kbeg) __syncthreads();
    *(short8*)&As[am_][ak] = vA;
    if (tBT) {
      *(short8*)&Bs[bn_][bkc]     = vB0;
      *(short8*)&Bs[bn_][bkc + 8] = vB1;
    } else {
      #pragma unroll
      for (int j = 0; j < 8; ++j) {
        Bs[bnc * 8 + j][bk2]      = vB0[j];
        Bs[bnc * 8 + j][bk2 + 16] = vB1[j];
      }
    }
    __syncthreads();
    int kn = k0 + 32;
    if (kn < kend) {
      loadA(kn, vA);
      if (tBT) loadBT(kn, vB0, vB1);
      else { loadBold(kn + bk2, vB0); loadBold(kn + bk2 + 16, vB1); }
    }
    short8 af[2], bfr[4];
    #pragma unroll
    for (int i = 0; i < 2; ++i)
      af[i] = *(const short8*)&As[wm * 32 + i * 16 + l16][quad * 8];
    #pragma unroll
    for (int j = 0; j < 4; ++j)
      bfr[j] = *(const short8*)&Bs[wn * 64 + j * 16 + l16][quad * 8];
    #pragma unroll
    for (int i = 0; i < 2; ++i)
      #pragma unroll
      for (int j = 0; j < 4; ++j)
        acc[i][j] = __builtin_amdgcn_mfma_f32_16x16x32_bf16(af[i], bfr[j], acc[i][j], 0, 0, 0);
  }

  #pragma unroll
  for (int i = 0; i < 2; ++i) {
    int m = m0 + wm * 32 + i * 16 + quad * 4;
    #pragma unroll
    for (int j = 0; j < 4; ++j) {
      int n = n0 + wn * 64 + j * 16 + l16;
      if (n >= N) continue;
      float bn_add = 0.f;
      if ((flags & 1) && ks == 0) {
        bn_add = (bias2 != nullptr && n >= Nsplit) ? ldt(bias2, n - Nsplit, tB)
                                                   : ldt(bias, oBias + n, tB);
      }
      #pragma unroll
      for (int r = 0; r < 4; ++r) {
        float v = acc[i][j][r] + bn_add;
        if ((flags & 2) && ks == 0) v += ldt(bias, oBias + m + r, tB);
        long off = baseC + (long)(m + r) * ldc + n;
        if (ksplit > 1) {
          atomicAdd((float*)C + off, v);
        } else {
          if (flags & 8) v += ldt(C, off, tC);
          if (flags & 4) v = fmaxf(v, 0.f);
          stt(C, off, tC, v);
        }
      }
    }
  }
}

// ---------------- encoder GEMM v2: K=256 resident A-tile, B fragments direct from L2 ----------------
// do_sm=1: softmax over each 16-col group for n >= Nsplit (fused attention-weight softmax).
__global__ __launch_bounds__(256) void egemm_kernel(const int* __restrict__ dflag,
    const void* __restrict__ A, const short* __restrict__ Bt,
    const void* __restrict__ bias, const void* __restrict__ bias2, void* __restrict__ C,
    int N, int ldc, int Nsplit, int tAc, int tCc, int do_sm) {
  int bf = *dflag;
  int tA = rt(tAc, bf), tC = rt(tCc, bf);
  int m0 = blockIdx.y * 64, n0 = blockIdx.x * 128;
  int tid = threadIdx.x;
  int wave = tid >> 6, lane = tid & 63;
  int wm = wave >> 1, wn = wave & 1;
  int quad = lane >> 4, l16 = lane & 15;

  __shared__ __align__(16) short As[64][264];

  floatx4 acc[2][4];
  #pragma unroll
  for (int i = 0; i < 2; ++i)
    #pragma unroll
    for (int j = 0; j < 4; ++j) acc[i][j] = floatx4{0.f, 0.f, 0.f, 0.f};

  // stage full A tile (64 x 256) once
  {
    int r = tid >> 2, c0 = (tid & 3) * 64;
    if (tA) {
      const short* s = (const short*)A + (long)(m0 + r) * 256 + c0;
      #pragma unroll
      for (int c = 0; c < 64; c += 8)
        *(short8*)&As[r][c0 + c] = *(const short8*)(s + c);
    } else {
      const float* f = (const float*)A + (long)(m0 + r) * 256 + c0;
      #pragma unroll
      for (int c = 0; c < 64; c += 8) {
        floatx4 f0 = *(const floatx4*)(f + c);
        floatx4 f1 = *(const floatx4*)(f + c + 4);
        short8 v;
        v[0]=f2bs(f0[0]); v[1]=f2bs(f0[1]); v[2]=f2bs(f0[2]); v[3]=f2bs(f0[3]);
        v[4]=f2bs(f1[0]); v[5]=f2bs(f1[1]); v[6]=f2bs(f1[2]); v[7]=f2bs(f1[3]);
        *(short8*)&As[r][c0 + c] = v;
      }
    }
  }
  __syncthreads();

  // barrier-free K loop; B fragments straight from L2
  #pragma unroll
  for (int k0 = 0; k0 < 256; k0 += 32) {
    short8 af[2], bfr[4];
    #pragma unroll
    for (int j = 0; j < 4; ++j)
      bfr[j] = *(const short8*)(Bt + (long)(n0 + wn * 64 + j * 16 + l16) * 256 + k0 + quad * 8);
    #pragma unroll
    for (int i = 0; i < 2; ++i)
      af[i] = *(const short8*)&As[wm * 32 + i * 16 + l16][k0 + quad * 8];
    #pragma unroll
    for (int i = 0; i < 2; ++i)
      #pragma unroll
      for (int j = 0; j < 4; ++j)
        acc[i][j] = __builtin_amdgcn_mfma_f32_16x16x32_bf16(af[i], bfr[j], acc[i][j], 0, 0, 0);
  }

  #pragma unroll
  for (int i = 0; i < 2; ++i) {
    int m = m0 + wm * 32 + i * 16 + quad * 4;
    #pragma unroll
    for (int j = 0; j < 4; ++j) {
      int n = n0 + wn * 64 + j * 16 + l16;
      if (n >= N) continue;
      float bn_add = (bias2 != nullptr && n >= Nsplit) ? ldt(bias2, n - Nsplit, bf)
                                                       : ldt(bias, n, bf);
      float vv[4];
      #pragma unroll
      for (int r = 0; r < 4; ++r) vv[r] = acc[i][j][r] + bn_add;
      if (do_sm && n0 + wn * 64 + j * 16 >= Nsplit) {
        #pragma unroll
        for (int r = 0; r < 4; ++r) {
          float x = vv[r];
          float mx = x;
          #pragma unroll
          for (int msk = 1; msk < 16; msk <<= 1)
            mx = fmaxf(mx, __shfl_xor(mx, msk));
          float e = expf(x - mx);
          float ssum = e;
          #pragma unroll
          for (int msk = 1; msk < 16; msk <<= 1)
            ssum += __shfl_xor(ssum, msk);
          vv[r] = e / ssum;
        }
      }
      #pragma unroll
      for (int r = 0; r < 4; ++r)
        stt(C, (long)(m + r) * ldc + n, tC, vv[r]);
    }
  }
}

// ---------------- fused FFN v7: async LDS staging, barrier BEFORE issue (latency hides under compute) ----------------
// out = relu(src@W1 + b1) @ W2 + b2. W1t [2048][256], W2t [256][2048].
__global__ __launch_bounds__(256) void ffn_kernel(const int* __restrict__ dflag,
    const float* __restrict__ src, const short* __restrict__ W1t, const void* __restrict__ b1,
    const short* __restrict__ W2t, const void* __restrict__ b2, bf16* __restrict__ out) {
  int bf = *dflag;
  long m0 = (long)blockIdx.x * 32;
  int tid = threadIdx.x;
  int wn = tid >> 6, lane = tid & 63;
  int quad = lane >> 4, l16 = lane & 15;

  __shared__ __align__(16) short As[32][264];   // src tile, K=256 resident
  __shared__ __align__(16) short Hs[32][136];   // hidden chunk (128 k)
  __shared__ __align__(16) short Bs3[3][4096];  // weight tile buffers [128][32]

  // per-lane staging map: n = slot*16 + lane/4, k = (lane&3)*8, slot = wn*2 + t
  int sn = lane >> 2, sk = (lane & 3) * 8;

  floatx4 acc2[2][4];
  #pragma unroll
  for (int i = 0; i < 2; ++i)
    #pragma unroll
    for (int j = 0; j < 4; ++j) acc2[i][j] = floatx4{0.f, 0.f, 0.f, 0.f};

  // stage src tile once (32 x 256)
  {
    int r = tid >> 3, c0 = (tid & 7) * 32;
    const float* sp = src + (m0 + r) * 256 + c0;
    #pragma unroll
    for (int c = 0; c < 32; c += 8) {
      floatx4 f0 = *(const floatx4*)(sp + c);
      floatx4 f1 = *(const floatx4*)(sp + c + 4);
      short8 v;
      v[0]=f2bs(f0[0]); v[1]=f2bs(f0[1]); v[2]=f2bs(f0[2]); v[3]=f2bs(f0[3]);
      v[4]=f2bs(f1[0]); v[5]=f2bs(f1[1]); v[6]=f2bs(f1[2]); v[7]=f2bs(f1[3]);
      *(short8*)&As[r][c0 + c] = v;
    }
  }

  auto stageW1 = [&](int buf, int ch, int k1) {
    #pragma unroll
    for (int t = 0; t < 2; ++t) {
      int slot = wn * 2 + t;
      int n = slot * 16 + sn;
      const short* gp = W1t + (long)(ch * 128 + n) * 256 + k1 + sk;
      gload_lds16(gp, &Bs3[buf][slot * 512]);
    }
  };
  auto stageW2 = [&](int buf, int ch, int t2) {
    int nh = t2 >> 2, k2 = (t2 & 3) * 32;
    #pragma unroll
    for (int t = 0; t < 2; ++t) {
      int slot = wn * 2 + t;
      int n = slot * 16 + sn;
      const short* gp = W2t + (long)(nh * 128 + n) * 2048 + ch * 128 + k2 + sk;
      gload_lds16(gp, &Bs3[buf][slot * 512]);
    }
  };

  __syncthreads();   // As visible

  for (int ch = 0; ch < 16; ++ch) {
    floatx4 acc1[2][2];
    #pragma unroll
    for (int i = 0; i < 2; ++i)
      #pragma unroll
      for (int j = 0; j < 2; ++j) acc1[i][j] = floatx4{0.f, 0.f, 0.f, 0.f};

    // ---- stage1: H = relu(src @ W1chunk) ----
    stageW1(0, ch, 0);
    #pragma unroll
    for (int s = 0; s < 8; ++s) {
      __syncthreads();   // buf[s%3] ready (issued >=1 phase ago; latency hidden under prev compute)
      if (s < 7) stageW1((s + 1) % 3, ch, (s + 1) * 32);
      const short* bb = &Bs3[s % 3][0];
      short8 af[2], bfr[2];
      #pragma unroll
      for (int j = 0; j < 2; ++j)
        bfr[j] = *(const short8*)(bb + (wn * 32 + j * 16 + l16) * 32 + quad * 8);
      #pragma unroll
      for (int i = 0; i < 2; ++i)
        af[i] = *(const short8*)&As[i * 16 + l16][s * 32 + quad * 8];
      #pragma unroll
      for (int i = 0; i < 2; ++i)
        #pragma unroll
        for (int j = 0; j < 2; ++j)
          acc1[i][j] = __builtin_amdgcn_mfma_f32_16x16x32_bf16(af[i], bfr[j], acc1[i][j], 0, 0, 0);
    }

    __syncthreads();     // all stage1 reads done (also guards Hs overwrite)
    stageW2(0, ch, 0);   // issue early; latency hides under Hs write
    #pragma unroll
    for (int i = 0; i < 2; ++i)
      #pragma unroll
      for (int j = 0; j < 2; ++j) {
        int nl = wn * 32 + j * 16 + l16;
        float bb = ldt(b1, (long)ch * 128 + nl, bf);
        #pragma unroll
        for (int r = 0; r < 4; ++r) {
          float hv = fmaxf(acc1[i][j][r] + bb, 0.f);
          Hs[i * 16 + quad * 4 + r][nl] = f2bs(hv);
        }
      }
    __syncthreads();     // Hs visible + stage2 buf0 drained (partially hidden)

    // ---- stage2: acc2 += H @ W2chunk ----
    #pragma unroll
    for (int s = 0; s < 8; ++s) {
      if (s) __syncthreads();   // buf[s%3] ready (issued one phase ago)
      if (s < 7) stageW2((s + 1) % 3, ch, s + 1);
      int nh = s >> 2;
      const short* bb = &Bs3[s % 3][0];
      short8 ah[2], bfr[2];
      #pragma unroll
      for (int j = 0; j < 2; ++j)
        bfr[j] = *(const short8*)(bb + (wn * 32 + j * 16 + l16) * 32 + quad * 8);
      int k2 = (s & 3) * 32;
      #pragma unroll
      for (int i = 0; i < 2; ++i)
        ah[i] = *(const short8*)&Hs[i * 16 + l16][k2 + quad * 8];
      #pragma unroll
      for (int i = 0; i < 2; ++i)
        #pragma unroll
        for (int j = 0; j < 2; ++j)
          acc2[i][nh * 2 + j] =
              __builtin_amdgcn_mfma_f32_16x16x32_bf16(ah[i], bfr[j], acc2[i][nh * 2 + j], 0, 0, 0);
    }
    __syncthreads();   // all stage2 reads done before next chunk's staging
  }

  #pragma unroll
  for (int i = 0; i < 2; ++i) {
    long m = m0 + i * 16 + quad * 4;
    #pragma unroll
    for (int nh = 0; nh < 2; ++nh)
      #pragma unroll
      for (int j = 0; j < 2; ++j) {
        int n = nh * 128 + wn * 32 + j * 16 + l16;
        float bb = ldt(b2, n, bf);
        #pragma unroll
        for (int r = 0; r < 4; ++r)
          out[(m + r) * 256 + n] = __float2bfloat16(acc2[i][nh * 2 + j][r] + bb);
      }
  }
}

// ---------------- 3x3 conv as MFMA implicit GEMM (pre-transposed bf16 weights) ----------------
__global__ __launch_bounds__(256) void mconv_kernel(const short* __restrict__ Wc,
    const float* __restrict__ X, float* __restrict__ Y, int H, int Wd, int lw) {
  int bz = blockIdx.z;
  int HW = H * Wd;
  const float* Xb = X + (long)bz * 256 * HW;
  float* Yb = Y + (long)bz * 256 * HW;
  int m0 = blockIdx.y * 64, n0 = blockIdx.x * 128;
  int tid = threadIdx.x;
  int wave = tid >> 6, lane = tid & 63;
  int wm = wave >> 1, wn = wave & 1;
  int quad = lane >> 4, l16 = lane & 15;

  __shared__ __align__(16) short As[64][40];
  __shared__ __align__(16) short Bs[128][40];

  floatx4 acc[2][4];
  #pragma unroll
  for (int i = 0; i < 2; ++i)
    #pragma unroll
    for (int j = 0; j < 4; ++j) acc[i][j] = floatx4{0.f, 0.f, 0.f, 0.f};

  int am_ = tid >> 2;
  int ak  = (tid & 3) * 8;
  int bn_ = tid & 127;
  int bkc = (tid >> 7) * 16;
  int gn  = n0 + bn_; if (gn >= HW) gn = HW - 1;
  int y = gn >> lw, x = gn & (Wd - 1);

  const short* Arow = Wc + (long)(m0 + am_) * 2304 + ak;

  short8 vA;
  float rB[16];
  auto pre = [&](int k0) {
    vA = *(const short8*)(Arow + k0);
    int tap = k0 >> 8;
    int dy = tap / 3 - 1, dx = tap % 3 - 1;
    bool ok = ((unsigned)(y + dy) < (unsigned)H) && ((unsigned)(x + dx) < (unsigned)Wd);
    const float* xp = Xb + (long)((k0 & 255) + bkc) * HW + gn + dy * Wd + dx;
    #pragma unroll
    for (int j = 0; j < 16; ++j)
      rB[j] = ok ? xp[(long)j * HW] : 0.f;
  };

  pre(0);
  for (int k0 = 0; k0 < 2304; k0 += 32) {
    if (k0) __syncthreads();
    *(short8*)&As[am_][ak] = vA;
    #pragma unroll
    for (int j = 0; j < 16; ++j) Bs[bn_][bkc + j] = f2bs(rB[j]);
    __syncthreads();
    if (k0 + 32 < 2304) pre(k0 + 32);
    short8 af[2], bfr[4];
    #pragma unroll
    for (int i = 0; i < 2; ++i)
      af[i] = *(const short8*)&As[wm * 32 + i * 16 + l16][quad * 8];
    #pragma unroll
    for (int j = 0; j < 4; ++j)
      bfr[j] = *(const short8*)&Bs[wn * 64 + j * 16 + l16][quad * 8];
    #pragma unroll
    for (int i = 0; i < 2; ++i)
      #pragma unroll
      for (int j = 0; j < 4; ++j)
        acc[i][j] = __builtin_amdgcn_mfma_f32_16x16x32_bf16(af[i], bfr[j], acc[i][j], 0, 0, 0);
  }

  #pragma unroll
  for (int i = 0; i < 2; ++i) {
    int m = m0 + wm * 32 + i * 16 + quad * 4;
    #pragma unroll
    for (int j = 0; j < 4; ++j) {
      int n = n0 + wn * 64 + j * 16 + l16;
      if (n >= HW) continue;
      #pragma unroll
      for (int r = 0; r < 4; ++r)
        Yb[(long)(m + r) * HW + n] = acc[i][j][r];
    }
  }
}

// ---------------- GroupNorm in-place (fp32 X) ----------------
__global__ __launch_bounds__(256) void gn_kernel(const int* __restrict__ dflag,
    float* __restrict__ X, const void* __restrict__ gs, const void* __restrict__ gb,
    long po, int HW, int relu) {
  int bf = *dflag;
  int g = blockIdx.x, b = blockIdx.y;
  float* base = X + ((long)b * 256 + g * 8) * HW;
  int n = 8 * HW;
  int t = threadIdx.x;
  float s1 = 0.f, s2 = 0.f;
  for (int i = t; i < n; i += 256) { float v = base[i]; s1 += v; s2 += v * v; }
  __shared__ float r1[256], r2[256];
  r1[t] = s1; r2[t] = s2; __syncthreads();
  for (int sh = 128; sh > 0; sh >>= 1) {
    if (t < sh) { r1[t] += r1[t + sh]; r2[t] += r2[t + sh]; }
    __syncthreads();
  }
  float mu = r1[0] / n;
  float var = fmaxf(r2[0] / n - mu * mu, 0.f);
  float inv = rsqrtf(var + 1e-5f);
  for (int i = t; i < n; i += 256) {
    int c = g * 8 + i / HW;
    float v = (base[i] - mu) * inv * ldt(gs, po + c, bf) + ldt(gb, po + c, bf);
    if (relu) v = fmaxf(v, 0.f);
    base[i] = v;
  }
}

// ---------------- bilinear 0.5x downsample (2x2 avg) added into target ----------------
__global__ __launch_bounds__(256) void dsadd_kernel(float* __restrict__ T,
    const float* __restrict__ P, int H, int Wd) {
  int idx = blockIdx.x * 256 + threadIdx.x;
  int total = BB * 256 * H * Wd;
  if (idx >= total) return;
  int x = idx % Wd, y = (idx / Wd) % H;
  int bc = idx / (Wd * H);
  const float* Pp = P + (((long)bc * (2 * H) + 2 * y) * (2 * Wd) + 2 * x);
  T[idx] += 0.25f * (Pp[0] + Pp[1] + Pp[2 * Wd] + Pp[2 * Wd + 1]);
}

// ---------------- build src (fp32) from FPN maps ----------------
__global__ __launch_bounds__(256) void srcbuild_kernel(const float* __restrict__ O0,
    const float* __restrict__ O1, const float* __restrict__ O2, const float* __restrict__ O3,
    float* __restrict__ src) {
  int idx = blockIdx.x * 256 + threadIdx.x;
  if (idx >= MTOT * 256) return;
  int c = idx & 255;
  int bs = idx >> 8;
  int s = bs % S_TOT, b = bs / S_TOT;
  int st, w, h; lvl_of(s, st, w, h);
  const float* O = (s < 4096) ? O0 : (s < 5120) ? O1 : (s < 5376) ? O2 : O3;
  int HW = w * h;
  src[idx] = O[((long)(b * 256 + c)) * HW + (s - st)];
}

// ---------------- layer-0 q = bf16(src + pos) ----------------
__global__ __launch_bounds__(256) void qinit_kernel(const float* __restrict__ src,
    bf16* __restrict__ q) {
  int idx = blockIdx.x * 256 + threadIdx.x;
  if (idx >= MTOT * 256) return;
  int c = idx & 255;
  int bs = idx >> 8;
  int s = bs % S_TOT;
  q[idx] = __float2bfloat16(src[idx] + pos_enc(s, c));
}

// ---------------- multi-scale deformable sampling, 4 d-channels per thread ----------------
__global__ __launch_bounds__(256) void deform_kernel(const bf16* __restrict__ value,
    const bf16* __restrict__ oaw, bf16* __restrict__ attn) {
  int idx = blockIdx.x * 256 + threadIdx.x;
  if (idx >= MTOT * 64) return;
  int d4 = idx & 7;          // which quad of d (d = d4*4 .. d4*4+3)
  int h = (idx >> 3) & 7;
  int bs = idx >> 6;
  int s = bs % S_TOT, b = bs / S_TOT;
  int stS, wS, hS; lvl_of(s, stS, wS, hS);
  int pl = s - stS;
  float rx = ((pl % wS) + 0.5f) / wS;
  float ry = ((pl / wS) + 0.5f) / hS;
  const bf16* offr = oaw + (long)bs * 384 + h * 32;
  const bf16* awr  = oaw + (long)bs * 384 + 256 + h * 16;
  const short* vbase = (const short*)value + (long)b * S_TOT * 256 + h * 32 + d4 * 4;
  const int LW[4] = {64, 32, 16, 8}, LST[4] = {0, 4096, 5120, 5376};
  float acc0 = 0.f, acc1 = 0.f, acc2 = 0.f, acc3 = 0.f;
  #pragma unroll
  for (int l = 0; l < 4; ++l) {
    int w = LW[l], hh = LW[l], st = LST[l];
    #pragma unroll
    for (int p = 0; p < 4; ++p) {
      float ox = __bfloat162float(offr[l * 8 + p * 2 + 0]);
      float oy = __bfloat162float(offr[l * 8 + p * 2 + 1]);
      float x = rx * w + ox - 0.5f;
      float y = ry * hh + oy - 0.5f;
      float x0f = floorf(x), y0f = floorf(y);
      int x0 = (int)x0f, y0 = (int)y0f;
      float fx = x - x0f, fy = y - y0f;
      float a = __bfloat162float(awr[l * 4 + p]);
      float s0 = 0.f, s1 = 0.f, s2 = 0.f, s3 = 0.f;
      #pragma unroll
      for (int ty2 = 0; ty2 < 2; ++ty2) {
        int yi = y0 + ty2;
        float wy = ty2 ? fy : 1.f - fy;
        bool vy = (yi >= 0) && (yi < hh);
        int yc = min(max(yi, 0), hh - 1);
        #pragma unroll
        for (int tx2 = 0; tx2 < 2; ++tx2) {
          int xi = x0 + tx2;
          float wx = tx2 ? fx : 1.f - fx;
          bool vx = (xi >= 0) && (xi < w);
          int xc = min(max(xi, 0), w - 1);
          short4v v = *(const short4v*)(vbase + (long)(st + yc * w + xc) * 256);
          float wxy = (vx && vy) ? wy * wx : 0.f;
          s0 += wxy * bs2f(v[0]);
          s1 += wxy * bs2f(v[1]);
          s2 += wxy * bs2f(v[2]);
          s3 += wxy * bs2f(v[3]);
        }
      }
      acc0 += a * s0; acc1 += a * s1; acc2 += a * s2; acc3 += a * s3;
    }
  }
  short4v o;
  o[0] = f2bs(acc0); o[1] = f2bs(acc1); o[2] = f2bs(acc2); o[3] = f2bs(acc3);
  *(short4v*)((short*)attn + (long)bs * 256 + h * 32 + d4 * 4) = o;
}

// ---------------- LayerNorm(src + resid_bf16), wave-per-row, optional q = bf16(out + pos) ----------------
__global__ __launch_bounds__(256) void ln_kernel(const int* __restrict__ dflag,
    float* __restrict__ src, const bf16* __restrict__ resid,
    const void* __restrict__ g, const void* __restrict__ b, bf16* __restrict__ qout) {
  int bf = *dflag;
  long r = (long)blockIdx.x * 4 + (threadIdx.x >> 6);
  int lane = threadIdx.x & 63;
  float* x = src + r * 256;
  const bf16* a = resid + r * 256;
  float v[4];
  float s1 = 0.f, s2 = 0.f;
  #pragma unroll
  for (int k = 0; k < 4; ++k) {
    int c = lane + 64 * k;
    float t = x[c] + __bfloat162float(a[c]);
    v[k] = t; s1 += t; s2 += t * t;
  }
  #pragma unroll
  for (int msk = 1; msk < 64; msk <<= 1) {
    s1 += __shfl_xor(s1, msk);
    s2 += __shfl_xor(s2, msk);
  }
  float mu = s1 * (1.f / 256.f);
  float var = fmaxf(s2 * (1.f / 256.f) - mu * mu, 0.f);
  float inv = rsqrtf(var + 1e-5f);
  int s = (int)(r % S_TOT);
  #pragma unroll
  for (int k = 0; k < 4; ++k) {
    int c = lane + 64 * k;
    float o = (v[k] - mu) * inv * ldt(g, c, bf) + ldt(b, c, bf);
    x[c] = o;
    if (qout) qout[r * 256 + c] = __float2bfloat16(o + pos_enc(s, c));
  }
}

// ---------------- unflatten src -> out chunks 1..4 ----------------
__global__ __launch_bounds__(256) void unflat_kernel(const int* __restrict__ dflag,
    const float* __restrict__ src, void* __restrict__ out) {
  int bf = *dflag;
  int idx = blockIdx.x * 256 + threadIdx.x;
  if (idx >= MTOT * 256) return;
  int c = idx & 255;
  int bs = idx >> 8;
  int s = bs % S_TOT, b = bs / S_TOT;
  int st, w, h; lvl_of(s, st, w, h);
  int HW = w * h;
  long base = (s < 4096) ? 2097152L : (s < 5120) ? 4194304L : (s < 5376) ? 4718592L : 4849664L;
  stt(out, base + ((long)(b * 256 + c)) * HW + (s - st), bf, src[idx]);
}

// ---------------- sentinel ----------------
__global__ __launch_bounds__(256) void sentinel_kernel(float* __restrict__ out, int n) {
  int i = blockIdx.x * 256 + threadIdx.x;
  if (i < n) out[i] = 999.0f;
}

// =====================================================================
extern "C" void kernel_launch(void* const* d_in, const int* in_sizes, int n_in,
                              void* d_out, int out_size, void* d_ws, size_t ws_size,
                              hipStream_t stream) {
  (void)in_sizes; (void)n_in;
  // 7,659,520 activations + 64 flag + 638,976 transposed-weight floats
  const size_t NEED = (7659520ull + 64ull + 638976ull) * 4ull;
  if (ws_size < NEED) {
    int nf = out_size / 2;
    sentinel_kernel<<<(nf + 255) / 256, 256, 0, stream>>>((float*)d_out, nf);
    return;
  }

  const void* feat[4] = {d_in[0], d_in[1], d_in[2], d_in[3]};
  const void* latw[4] = {d_in[4], d_in[5], d_in[6], d_in[7]};
  const void *latgns = d_in[8], *latgnb = d_in[9];
  const void* outw = d_in[10];
  const void *outgns = d_in[11], *outgnb = d_in[12];
  const void *offw = d_in[13], *offb_ = d_in[14], *aww = d_in[15], *awb_ = d_in[16];
  const void *valw = d_in[17], *valb_ = d_in[18], *projw = d_in[19], *projb_ = d_in[20];
  const void *f1w = d_in[21], *f1b = d_in[22], *f2w = d_in[23], *f2b = d_in[24];
  const void *ln1s = d_in[25], *ln1b = d_in[26], *ln2s = d_in[27], *ln2b = d_in[28];
  const void *maskw = d_in[29], *maskb = d_in[30];

  float* W = (float*)d_ws;
  float* srcb  = W;
  float* fpn_a = W;
  bf16*  oawbf = (bf16*)(W + 2785280);
  bf16*  tmpbf = oawbf;
  bf16*  qbf   = (bf16*)(W + 4874240);
  bf16*  valbf = (bf16*)(W + 6266880);
  float* ObF   = W + 4874240;
  float* Ob[4] = {ObF, ObF + 2097152, ObF + 2621440, ObF + 2752512};
  int*   dflag = (int*)(W + 7659520);
  short* wtS   = (short*)(W + 7659584);
  short* valt  = wtS;             // [256][256]
  short* projt = wtS + 65536;     // [256][256]
  short* oawt  = wtS + 131072;    // [384][256]
  short* w1t   = wtS + 229376;    // [2048][256]
  short* w2t   = wtS + 753664;    // [256][2048]
  // conv weights (bf16, [4][256][2304]) live in the encoder-phase oawbf region;
  // FPN finishes before the encoder overwrites it.
  short* wconvt = (short*)(W + 2785280);   // 2,359,296 shorts, ends at W+3964928

  detect_kernel<<<1, 1, 0, stream>>>(ln1s, dflag);
  // pre-transpose encoder weights to bf16 [N][K]
  wtrans_kernel<<<(65536 + 255) / 256, 256, 0, stream>>>(dflag, valw, valt, 256, 256);
  wtrans_kernel<<<(65536 + 255) / 256, 256, 0, stream>>>(dflag, projw, projt, 256, 256);
  wtrans_kernel<<<(65536 + 255) / 256, 256, 0, stream>>>(dflag, offw, oawt, 256, 256);
  wtrans_kernel<<<(32768 + 255) / 256, 256, 0, stream>>>(dflag, aww, oawt + 65536, 256, 128);
  wtrans_kernel<<<(524288 + 255) / 256, 256, 0, stream>>>(dflag, f1w, w1t, 256, 2048);
  wtrans_kernel<<<(524288 + 255) / 256, 256, 0, stream>>>(dflag, f2w, w2t, 2048, 256);
  wconvt_kernel<<<(2359296 + 255) / 256, 256, 0, stream>>>(dflag, outw, wconvt);

  const int M = MTOT;
  auto mgemm = [&](const void* A, const void* B, const void* bias, const void* bias2,
                   void* C, int Mi, int Ni, int Ki, int lda, int ldb, int ldc, int Nsplit,
                   long sA, long sB, long sC, long oB, long oBias, long oC,
                   int batch, int flags, int tA, int tB, int tC, int tBT, int ksplit) {
    dim3 g((Ni + 127) / 128, Mi / 64, batch * ksplit);
    mgemm_kernel<<<g, 256, 0, stream>>>(dflag, A, B, bias, bias2, C, Mi, Ni, Ki,
                                        lda, ldb, ldc, Nsplit,
                                        sA, sB, sC, oB, oBias, oC, flags, tA, tB, tC, tBT,
                                        ksplit);
  };
  auto egemm = [&](const void* A, const short* Bt, const void* bias, const void* bias2,
                   void* C, int Ni, int ldc, int Nsplit, int tA, int tC, int do_sm) {
    dim3 g((Ni + 127) / 128, M / 64, 1);
    egemm_kernel<<<g, 256, 0, stream>>>(dflag, A, Bt, bias, bias2, C, Ni, ldc, Nsplit,
                                        tA, tC, do_sm);
  };

  // ---------------- FPN ----------------
  const int LVL[4] = {64, 32, 16, 8};
  const int LGW[4] = {6, 5, 4, 3};
  const int CIN[4] = {256, 512, 1024, 2048};
  const int KSP[4] = {1, 4, 8, 16};   // split-K for under-parallelized laterals
  for (int i = 0; i < 4; ++i) {
    int H = LVL[i], HW = H * H, Cin = CIN[i];
    int ksp = KSP[i];
    if (ksp > 1)
      zero_kernel<<<(BB * 256 * HW + 255) / 256, 256, 0, stream>>>(fpn_a, BB * 256 * HW);
    mgemm(latw[i], feat[i], nullptr, nullptr, fpn_a, 256, HW, Cin,
          Cin, HW, HW, 0, 0, (long)Cin * HW, (long)256 * HW, 0, 0, 0, BB, 0, 2, 2, 0, 0, ksp);
    gn_kernel<<<dim3(32, BB), 256, 0, stream>>>(dflag, fpn_a, latgns, latgnb,
                                                (long)i * 256, HW, 0);
    if (i > 0) {
      int total = BB * 256 * HW;
      dsadd_kernel<<<(total + 255) / 256, 256, 0, stream>>>(fpn_a, Ob[i - 1], H, H);
    }
    {
      dim3 g((HW + 127) / 128, 4, BB);
      mconv_kernel<<<g, 256, 0, stream>>>(wconvt + (long)i * 589824, fpn_a, Ob[i],
                                          H, H, LGW[i]);
    }
    gn_kernel<<<dim3(32, BB), 256, 0, stream>>>(dflag, Ob[i], outgns, outgnb,
                                                (long)i * 256, HW, 1);
  }

  srcbuild_kernel<<<(M * 256) / 256, 256, 0, stream>>>(Ob[0], Ob[1], Ob[2], Ob[3], srcb);
  // layer-0 q (runs after srcbuild fully consumed Ob; qbf aliases Ob[0] safely now)
  qinit_kernel<<<(M * 256) / 256, 256, 0, stream>>>(srcb, qbf);

  // ---------------- encoder layers (shared weights) ----------------
  for (int L = 0; L < 6; ++L) {
    egemm(srcb, valt, valb_, nullptr, valbf, 256, 256, 256, 0, 1, 0);
    egemm(qbf, oawt, offb_, awb_, oawbf, 384, 384, 256, 1, 1, 1);   // fused aw softmax
    deform_kernel<<<(M * 64) / 256, 256, 0, stream>>>(valbf, oawbf, qbf);
    egemm(qbf, projt, projb_, nullptr, tmpbf, 256, 256, 256, 1, 1, 0);
    ln_kernel<<<M / 4, 256, 0, stream>>>(dflag, srcb, tmpbf, ln1s, ln1b, nullptr);
    ffn_kernel<<<M / 32, 256, 0, stream>>>(dflag, srcb, w1t, f1b, w2t, f2b, tmpbf);
    ln_kernel<<<M / 4, 256, 0, stream>>>(dflag, srcb, tmpbf, ln2s, ln2b,
                                         (L < 5) ? qbf : nullptr);
  }

  // ---------------- outputs ----------------
  unflat_kernel<<<(M * 256) / 256, 256, 0, stream>>>(dflag, srcb, d_out);
  mgemm(maskw, d_out, maskb, nullptr, d_out, 256, 4096, 256,
        256, 4096, 4096, 0, 0, 1048576L, 1048576L, 2097152L, 0, 0, BB, 2, 2, 2, 2, 0, 1);
}